// Round 3
// baseline (414.791 us; speedup 1.0000x reference)
//
#include <hip/hip_runtime.h>
#include <hip/hip_fp16.h>

#define NB 2049
#define TF 600
#define WINF 300
#define NFFT 4096
#define HOP 1024
#define ALEN 613376
#define EPSV 1e-10f
#define SQEPS 1e-5f
#define RCH 10
#define RCHT 30

// LDS padding for the legacy block-FFT fallback path
#define PADI(i) ((i) + ((i) >> 4))

__device__ __forceinline__ float2 cmul(float2 a, float2 b) {
  return make_float2(a.x*b.x - a.y*b.y, a.x*b.y + a.y*b.x);
}

__device__ __forceinline__ float2 h2f2(float w) {
  union { float f; __half2 h; } u; u.f = w;
  return __half22float2(u.h);
}

__global__ __launch_bounds__(256) void k_init(unsigned int* c2max) {
  if (blockIdx.x == 0 && threadIdx.x < 4) c2max[threadIdx.x] = 0u;
}

// ---- K1: per-window max |mix|^2 -------------------------------------------
__global__ __launch_bounds__(256) void k_maxred(const float* __restrict__ mix,
                                                unsigned int* __restrict__ c2max) {
  int winid = blockIdx.x >> 6;
  int blk = blockIdx.x & 63;
  const float4* p = (const float4*)(mix + (size_t)winid * (WINF * NB * 2 * 2));
  const int n4 = WINF * NB * 2 * 2 / 4;
  float m = 0.f;
  for (int i = blk * 256 + threadIdx.x; i < n4; i += 64 * 256) {
    float4 v = p[i];
    m = fmaxf(m, fmaxf(v.x*v.x + v.y*v.y, v.z*v.z + v.w*v.w));
  }
  for (int off = 32; off; off >>= 1) m = fmaxf(m, __shfl_xor(m, off));
  __shared__ float sm[4];
  if ((threadIdx.x & 63) == 0) sm[threadIdx.x >> 6] = m;
  __syncthreads();
  if (threadIdx.x == 0) {
    m = fmaxf(fmaxf(sm[0], sm[1]), fmaxf(sm[2], sm[3]));
    atomicMax(c2max + winid, __float_as_uint(m));
  }
}

// ---- K2a: covariance partials, lane = f (coalesced) -----------------------
// part[win][chunk][f][s][4]
__global__ __launch_bounds__(256) void k_rmat_part(const float* __restrict__ spec,
                                                   const float* __restrict__ mix,
                                                   float* __restrict__ part) {
  int ftile = blockIdx.x % 9;
  int chunk = (blockIdx.x / 9) % RCH;
  int winid = blockIdx.x / (9 * RCH);
  int f = ftile * 256 + threadIdx.x;
  if (f >= NB) return;
  int b = winid >> 1, w = winid & 1;
  float acc[16];
#pragma unroll
  for (int i = 0; i < 16; i++) acc[i] = 0.f;
  for (int tt = 0; tt < RCHT; tt++) {
    int t = w * WINF + chunk * RCHT + tt;
    size_t base = (size_t)(b * TF + t) * NB + f;
    const float4* sp = (const float4*)(spec + base * 8);
    float4 s0 = sp[0], s1 = sp[1];
    float4 mx = *(const float4*)(mix + base * 4);
    float n0 = mx.x*mx.x + mx.y*mx.y;
    float n1 = mx.z*mx.z + mx.w*mx.w;
    float qr, qi;
    if (n0 > 0.f && n1 > 0.f) {
      float inv = rsqrtf(n0 * n1);
      qr = (mx.x*mx.z + mx.y*mx.w) * inv;
      qi = (mx.y*mx.z - mx.x*mx.w) * inv;
    } else if (n0 > 0.f) { float inv = rsqrtf(n0); qr = mx.x*inv; qi = mx.y*inv; }
    else if (n1 > 0.f)   { float inv = rsqrtf(n1); qr = mx.z*inv; qi = -mx.w*inv; }
    else { qr = 1.f; qi = 0.f; }
    float A0[4] = {s0.x, s0.y, s0.z, s0.w};
    float A1[4] = {s1.x, s1.y, s1.z, s1.w};
#pragma unroll
    for (int s = 0; s < 4; s++) {
      acc[s*4+0] += A0[s]*A0[s];
      acc[s*4+1] += A1[s]*A1[s];
      float aa = A0[s]*A1[s];
      acc[s*4+2] += aa * qr;
      acc[s*4+3] += aa * qi;
    }
  }
  float* pp = part + (((size_t)winid * RCH + chunk) * NB + f) * 16;
#pragma unroll
  for (int s = 0; s < 4; s++)
    *(float4*)(pp + s*4) = make_float4(acc[s*4+0], acc[s*4+1], acc[s*4+2], acc[s*4+3]);
}

// ---- K2b: reduce partials + normalize -> Rbuf -----------------------------
__global__ __launch_bounds__(256) void k_rmat_red(const float* __restrict__ part,
                                                  const unsigned int* __restrict__ c2max,
                                                  float* __restrict__ Rbuf) {
  int idx = blockIdx.x * 256 + threadIdx.x;
  if (idx >= 4 * NB * 4) return;
  int s = idx & 3;
  int f = (idx >> 2) % NB;
  int winid = idx / (NB * 4);
  float4 a = make_float4(0.f, 0.f, 0.f, 0.f);
#pragma unroll
  for (int ch = 0; ch < RCH; ch++) {
    float4 p = *(const float4*)(part + (((size_t)winid * RCH + ch) * NB + f) * 16 + s * 4);
    a.x += p.x; a.y += p.y; a.z += p.z; a.w += p.w;
  }
  float c = fmaxf(1.f, sqrtf(__uint_as_float(c2max[winid])) * 0.1f);
  float W = c * c * EPSV + 0.5f * (a.x + a.y);
  float invW = 1.f / W;
  *(float4*)(Rbuf + ((size_t)winid * NB + f) * 16 + s * 4) =
      make_float4(a.x*invW, a.y*invW, a.z*invW, a.w*invW);
}

// ---- legacy K2 (fallback only) --------------------------------------------
__global__ __launch_bounds__(256) void k_rmat(const float* __restrict__ spec,
                                              const float* __restrict__ mix,
                                              const unsigned int* __restrict__ c2max,
                                              float* __restrict__ Rbuf) {
  int f = blockIdx.x;
  int winid = threadIdx.x >> 6;
  int lane = threadIdx.x & 63;
  int b = winid >> 1, w = winid & 1;
  float acc[16];
#pragma unroll
  for (int i = 0; i < 16; i++) acc[i] = 0.f;
  for (int tl = lane; tl < WINF; tl += 64) {
    int t = w * WINF + tl;
    size_t base = (size_t)(b * TF + t) * NB + f;
    const float4* sp = (const float4*)(spec + base * 8);
    float4 s0 = sp[0], s1 = sp[1];
    float4 mx = *(const float4*)(mix + base * 4);
    float n0 = mx.x*mx.x + mx.y*mx.y;
    float n1 = mx.z*mx.z + mx.w*mx.w;
    float qr, qi;
    if (n0 > 0.f && n1 > 0.f) {
      float inv = rsqrtf(n0 * n1);
      qr = (mx.x*mx.z + mx.y*mx.w) * inv;
      qi = (mx.y*mx.z - mx.x*mx.w) * inv;
    } else if (n0 > 0.f) { float inv = rsqrtf(n0); qr = mx.x*inv; qi = mx.y*inv; }
    else if (n1 > 0.f)   { float inv = rsqrtf(n1); qr = mx.z*inv; qi = -mx.w*inv; }
    else { qr = 1.f; qi = 0.f; }
    float A0[4] = {s0.x, s0.y, s0.z, s0.w};
    float A1[4] = {s1.x, s1.y, s1.z, s1.w};
#pragma unroll
    for (int s = 0; s < 4; s++) {
      acc[s*4+0] += A0[s]*A0[s];
      acc[s*4+1] += A1[s]*A1[s];
      float aa = A0[s]*A1[s];
      acc[s*4+2] += aa * qr;
      acc[s*4+3] += aa * qi;
    }
  }
#pragma unroll
  for (int i = 0; i < 16; i++) {
#pragma unroll
    for (int off = 32; off; off >>= 1) acc[i] += __shfl_xor(acc[i], off);
  }
  if (lane == 0) {
    float c = fmaxf(1.f, sqrtf(__uint_as_float(c2max[winid])) * 0.1f);
    float c2 = c * c;
#pragma unroll
    for (int s = 0; s < 4; s++) {
      float W = c2 * EPSV + 0.5f * (acc[s*4+0] + acc[s*4+1]);
      float invW = 1.f / W;
      *(float4*)(Rbuf + ((size_t)winid * NB + f) * 16 + s * 4) =
          make_float4(acc[s*4+0]*invW, acc[s*4+1]*invW, acc[s*4+2]*invW, acc[s*4+3]*invW);
    }
  }
}

// ---- K3: EM apply, write Y (fp16 complex) in [b][s][c][t][f] --------------
__global__ __launch_bounds__(256) void k_apply(const float* __restrict__ spec,
                                               const float* __restrict__ mix,
                                               const unsigned int* __restrict__ c2max,
                                               const float* __restrict__ Rbuf,
                                               __half2* __restrict__ Y) {
  size_t idx = (size_t)blockIdx.x * 256 + threadIdx.x;
  if (idx >= (size_t)2 * TF * NB) return;
  int f = (int)(idx % NB);
  int r = (int)(idx / NB);
  int t = r % TF, b = r / TF;
  int winid = b * 2 + (t >= WINF ? 1 : 0);
  float c = fmaxf(1.f, sqrtf(__uint_as_float(c2max[winid])) * 0.1f);
  float invc = 1.f / c, inv2c2 = 0.5f * invc * invc;
  size_t base = (size_t)(b * TF + t) * NB + f;
  const float4* sp = (const float4*)(spec + base * 8);
  float4 s0v = sp[0], s1v = sp[1];
  float4 mx = *(const float4*)(mix + base * 4);
  const float4* Rp = (const float4*)(Rbuf + ((size_t)winid * NB + f) * 16);
  float A0[4] = {s0v.x, s0v.y, s0v.z, s0v.w};
  float A1[4] = {s1v.x, s1v.y, s1v.z, s1v.w};
  float v[4]; float4 R[4];
  float C00 = SQEPS, C11 = SQEPS, C01r = 0.f, C01i = 0.f;
#pragma unroll
  for (int sq = 0; sq < 4; sq++) {
    R[sq] = Rp[sq];
    v[sq] = (A0[sq]*A0[sq] + A1[sq]*A1[sq]) * inv2c2;
    C00 += v[sq]*R[sq].x; C11 += v[sq]*R[sq].y;
    C01r += v[sq]*R[sq].z; C01i += v[sq]*R[sq].w;
  }
  float det = C00*C11 - (C01r*C01r + C01i*C01i);
  float invdet = 1.f / det;
  float x0r = mx.x*invc, x0i = mx.y*invc, x1r = mx.z*invc, x1i = mx.w*invc;
  float ix0r = (C11*x0r - (C01r*x1r - C01i*x1i)) * invdet;
  float ix0i = (C11*x0i - (C01r*x1i + C01i*x1r)) * invdet;
  float ix1r = (C00*x1r - (C01r*x0r + C01i*x0i)) * invdet;
  float ix1i = (C00*x1i - (C01r*x0i - C01i*x0r)) * invdet;
#pragma unroll
  for (int sq = 0; sq < 4; sq++) {
    float vc = v[sq] * c;
    float y0r = vc*(R[sq].x*ix0r + R[sq].z*ix1r - R[sq].w*ix1i);
    float y0i = vc*(R[sq].x*ix0i + R[sq].z*ix1i + R[sq].w*ix1r);
    float y1r = vc*(R[sq].z*ix0r + R[sq].w*ix0i + R[sq].y*ix1r);
    float y1i = vc*(R[sq].z*ix0i - R[sq].w*ix0r + R[sq].y*ix1i);
    size_t pbase = ((size_t)((b * 4 + sq) * 2) * TF + t) * NB + f;
    Y[pbase] = __floats2half2_rn(y0r, y0i);
    Y[pbase + (size_t)TF * NB] = __floats2half2_rn(y1r, y1i);
  }
}

// ---- K4: wave-private ISTFT. 1 wave = 1 frame FFT, no inner barriers ------
__global__ __launch_bounds__(256) void k_istft_wave(const __half2* __restrict__ Y,
                                                    float* __restrict__ out) {
  __shared__ float2 acc[4][2048];
  const int tid = threadIdx.x;
  const int lane = tid & 63;
  const int wv = tid >> 6;
  const int u = blockIdx.x % 150;
  const int sid = blockIdx.x / 150;
  const int M0 = 2048 + u * 4096;
  const int t0 = max(0, 4*u - 1);
  const int t1 = min(TF - 1, 4*u + 5);

  // zero own accumulator (wave-private, no barrier needed)
#pragma unroll
  for (int i = 0; i < 32; i++) acc[wv][lane + 64*i] = make_float2(0.f, 0.f);

  // bit-reverse(lane, 6 bits)
  const int m1 = ((lane & 1) << 5) | ((lane & 2) << 3) | ((lane & 4) << 1)
               | ((lane & 8) >> 1) | ((lane & 16) >> 3) | ((lane & 32) >> 5);

  constexpr float TC[16] = {1.f, 0.980785280403230f, 0.923879532511287f, 0.831469612302545f,
                            0.707106781186548f, 0.555570233019602f, 0.382683432365090f, 0.195090322016128f,
                            0.f, -0.195090322016128f, -0.382683432365090f, -0.555570233019602f,
                            -0.707106781186548f, -0.831469612302545f, -0.923879532511287f, -0.980785280403230f};
  constexpr float TS[16] = {0.f, 0.195090322016128f, 0.382683432365090f, 0.555570233019602f,
                            0.707106781186548f, 0.831469612302545f, 0.923879532511287f, 0.980785280403230f,
                            1.f, 0.980785280403230f, 0.923879532511287f, 0.831469612302545f,
                            0.707106781186548f, 0.555570233019602f, 0.382683432365090f, 0.195090322016128f};

  for (int t = t0 + wv; t <= t1; t += 4) {
    const unsigned* Yu = (const unsigned*)(Y + ((size_t)sid * TF + t) * NB);
    // raw half2 words, k = 32*lane + r
    float wa[32];
#pragma unroll
    for (int r = 0; r < 32; r++) wa[r] = __uint_as_float(Yu[32*lane + r]);
    float y2048w = __uint_as_float(Yu[2048]);

    // fold: Z[k] = 0.5*[(Sx - sn*Dx - cs*Dy) + i(Sy + cs*Dx - sn*Dy)]
    float2 v[32];
    float fsn, fcs;
    __sincosf((float)lane * 0.0490873852123405f /* pi/64 */, &fsn, &fcs);
    float2 ph = make_float2(fcs, fsn);                       // e^{i*pi*k/2048}, k=32*lane
    const float STC = 0.9999988234517019f, STS = 0.0015339801862847657f; // e^{i*pi/2048}
#pragma unroll
    for (int r = 0; r < 32; r++) {
      float ybw;
      if (r == 0) {
        ybw = __shfl(wa[0], (64 - lane) & 63);
        if (lane == 0) ybw = y2048w;
      } else {
        ybw = __shfl(wa[32 - r], 63 - lane);
      }
      float2 Xa = h2f2(wa[r]);
      float2 Xb = h2f2(ybw);
      if (r == 0 && lane == 0) { Xa.y = 0.f; Xb.y = 0.f; }
      float Sx = Xa.x + Xb.x, Sy = Xa.y - Xb.y;
      float Dx = Xa.x - Xb.x, Dy = Xa.y + Xb.y;
      float cs = ph.x, sn = ph.y;
      v[r] = make_float2(0.5f*(Sx - sn*Dx - cs*Dy), 0.5f*(Sy + cs*Dx - sn*Dy));
      if (r < 31) ph = make_float2(ph.x*STC - ph.y*STS, ph.x*STS + ph.y*STC);
    }

    // cross-lane inverse DIF FFT-64 (masks 32..1)
#pragma unroll
    for (int si = 0; si < 6; ++si) {
      const int h = 32 >> si;
      float sn, cs;
      __sincosf((float)(lane & (h - 1)) * (3.14159265358979f / (float)h), &sn, &cs);
      const bool hi = (lane & h) != 0;
      const float wr = hi ? cs : 1.f;
      const float wi = hi ? sn : 0.f;
      const float sg = hi ? -1.f : 1.f;
#pragma unroll
      for (int r = 0; r < 32; ++r) {
        float ox = __shfl_xor(v[r].x, h);
        float oy = __shfl_xor(v[r].y, h);
        float ax = fmaf(sg, v[r].x, ox);
        float ay = fmaf(sg, v[r].y, oy);
        v[r].x = ax*wr - ay*wi;
        v[r].y = ax*wi + ay*wr;
      }
    }

    // twiddle e^{i*m1*r*2pi/2048} via chain
    {
      float bsn, bcs;
      __sincosf((float)m1 * 0.0030679615757712823f /* pi/1024 */, &bsn, &bcs);
      float2 cw = make_float2(bcs, bsn);
#pragma unroll
      for (int r = 1; r < 32; ++r) {
        float nx = v[r].x*cw.x - v[r].y*cw.y;
        float ny = v[r].x*cw.y + v[r].y*cw.x;
        v[r].x = nx; v[r].y = ny;
        if (r < 31) cw = make_float2(cw.x*bcs - cw.y*bsn, cw.x*bsn + cw.y*bcs);
      }
    }

    // in-register inverse DIF FFT-32
#define R32STAGE(HH)                                                        \
    _Pragma("unroll") for (int bb = 0; bb < 32; bb += 2*(HH)) {             \
      _Pragma("unroll") for (int j = 0; j < (HH); ++j) {                    \
        float2 a = v[bb+j], c = v[bb+j+(HH)];                               \
        v[bb+j] = make_float2(a.x+c.x, a.y+c.y);                            \
        float dx = a.x-c.x, dy = a.y-c.y;                                   \
        const float tc = TC[j*(16/(HH))], ts = TS[j*(16/(HH))];             \
        v[bb+j+(HH)] = make_float2(dx*tc - dy*ts, dx*ts + dy*tc);           \
      }                                                                     \
    }
    R32STAGE(16) R32STAGE(8) R32STAGE(4) R32STAGE(2) R32STAGE(1)
#undef R32STAGE

    // windowed overlap-add into wave-private accumulator
    const int off2 = (t << 9) - (M0 >> 1);
#pragma unroll
    for (int p = 0; p < 32; ++p) {
      const int m2 = ((p&1)<<4) | ((p&2)<<2) | (p&4) | ((p&8)>>2) | ((p&16)>>4);
      int m = m1 + (m2 << 6);
      int i2 = m + off2;
      if ((unsigned)i2 < 2048u) {
        float we = 0.5f - 0.5f*__cosf((float)m * 0.0030679615757712823f);
        float wo = 0.5f - 0.5f*__cosf((float)(2*m+1) * 0.0015339807878856412f);
        float2 A = acc[wv][i2];
        A.x += v[p].x * we;
        A.y += v[p].y * wo;
        acc[wv][i2] = A;
      }
    }
  }

  __syncthreads();

  // combine 4 wave accumulators, divide by wsum (exactly 1.5 interior)
  const float inv2048 = 1.f/2048.f;
#pragma unroll
  for (int q = 0; q < 8; ++q) {
    int i2 = tid + 256*q;
    float2 s0 = acc[0][i2], s1 = acc[1][i2], s2 = acc[2][i2], s3 = acc[3][i2];
    float sx = s0.x + s1.x + s2.x + s3.x;
    float sy = s0.y + s1.y + s2.y + s3.y;
    float we = 1.5f, wo = 1.5f;
    if (u == 0 || u == 149) {
      we = 0.f; wo = 0.f;
      int ne = M0 + 2*i2;
      for (int t = t0; t <= t1; ++t) {
        int j = ne - (t << 10);
        if ((unsigned)j < 4096u) {
          float w = 0.5f - 0.5f*__cosf((float)j * 0.0015339807878856412f);
          we += w*w;
        }
        int j1 = j + 1;
        if ((unsigned)j1 < 4096u) {
          float w = 0.5f - 0.5f*__cosf((float)j1 * 0.0015339807878856412f);
          wo += w*w;
        }
      }
      we = (we > 1e-11f) ? we : 1.f;
      wo = (wo > 1e-11f) ? wo : 1.f;
    }
    int o = u*4096 + 2*i2;
    if (o < ALEN) {
      float2 rv = make_float2(sx * inv2048 / we, sy * inv2048 / wo);
      *(float2*)(out + (size_t)sid * ALEN + o) = rv;
    }
  }
}

// ---- legacy fused path (fallback if ws too small) -------------------------
__device__ __forceinline__ float2 em_point_one(const float* __restrict__ spec,
    const float* __restrict__ mix, const float* __restrict__ Rbuf,
    const unsigned int* __restrict__ c2max, int b, int t, int f, int ssel, int ch) {
  int winid = b * 2 + (t >= WINF ? 1 : 0);
  float c = fmaxf(1.f, sqrtf(__uint_as_float(c2max[winid])) * 0.1f);
  float invc = 1.f / c, inv2c2 = 0.5f * invc * invc;
  size_t base = (size_t)(b * TF + t) * NB + f;
  const float4* sp = (const float4*)(spec + base * 8);
  float4 s0 = sp[0], s1 = sp[1];
  float4 mx = *(const float4*)(mix + base * 4);
  const float4* Rp = (const float4*)(Rbuf + ((size_t)winid * NB + f) * 16);
  float A0v[4] = {s0.x, s0.y, s0.z, s0.w};
  float A1v[4] = {s1.x, s1.y, s1.z, s1.w};
  float C00 = SQEPS, C11 = SQEPS, C01r = 0.f, C01i = 0.f;
  float vsel = 0.f; float4 Rsel = make_float4(0.f, 0.f, 0.f, 0.f);
#pragma unroll
  for (int sq = 0; sq < 4; sq++) {
    float4 R = Rp[sq];
    float v = (A0v[sq]*A0v[sq] + A1v[sq]*A1v[sq]) * inv2c2;
    C00 += v*R.x; C11 += v*R.y; C01r += v*R.z; C01i += v*R.w;
    if (sq == ssel) { vsel = v; Rsel = R; }
  }
  float det = C00*C11 - (C01r*C01r + C01i*C01i);
  float invdet = 1.f / det;
  float x0r = mx.x*invc, x0i = mx.y*invc, x1r = mx.z*invc, x1i = mx.w*invc;
  float ix0r = (C11*x0r - (C01r*x1r - C01i*x1i)) * invdet;
  float ix0i = (C11*x0i - (C01r*x1i + C01i*x1r)) * invdet;
  float ix1r = (C00*x1r - (C01r*x0r + C01i*x0i)) * invdet;
  float ix1i = (C00*x1i - (C01r*x0i - C01i*x0r)) * invdet;
  float vc = vsel * c;
  if (ch == 0)
    return make_float2(vc*(Rsel.x*ix0r + Rsel.z*ix1r - Rsel.w*ix1i),
                       vc*(Rsel.x*ix0i + Rsel.z*ix1i + Rsel.w*ix1r));
  return make_float2(vc*(Rsel.z*ix0r + Rsel.w*ix0i + Rsel.y*ix1r),
                     vc*(Rsel.z*ix0i - Rsel.w*ix0r + Rsel.y*ix1i));
}

template<int NS>
__device__ __forceinline__ void r4stage(const float2* __restrict__ src,
                                        float2* __restrict__ dst, int tid) {
#pragma unroll
  for (int qq = 0; qq < 2; qq++) {
    int q = tid + qq * 256;
    int jm = q & (NS - 1);
    float2 v0 = src[PADI(q)];
    float2 v1 = src[PADI(q + 512)];
    float2 v2 = src[PADI(q + 1024)];
    float2 v3 = src[PADI(q + 1536)];
    if constexpr (NS > 1) {
      float sn, cs;
      __sincosf((float)jm * (1.5707963267948966f / (float)NS), &sn, &cs);
      float2 w1 = make_float2(cs, sn);
      float2 w2 = cmul(w1, w1);
      float2 w3 = cmul(w2, w1);
      v1 = cmul(v1, w1);
      v2 = cmul(v2, w2);
      v3 = cmul(v3, w3);
    }
    float2 a0 = make_float2(v0.x + v2.x, v0.y + v2.y);
    float2 a1 = make_float2(v0.x - v2.x, v0.y - v2.y);
    float2 a2 = make_float2(v1.x + v3.x, v1.y + v3.y);
    float2 a3 = make_float2(v1.x - v3.x, v1.y - v3.y);
    int d = ((q - jm) << 2) + jm;
    dst[PADI(d)]        = make_float2(a0.x + a2.x, a0.y + a2.y);
    dst[PADI(d + NS)]   = make_float2(a1.x - a3.y, a1.y + a3.x);
    dst[PADI(d + 2*NS)] = make_float2(a0.x - a2.x, a0.y - a2.y);
    dst[PADI(d + 3*NS)] = make_float2(a1.x + a3.y, a1.y - a3.x);
  }
}

__device__ __forceinline__ void r2stage(const float2* __restrict__ src,
                                        float2* __restrict__ dst, int tid) {
#pragma unroll
  for (int qq = 0; qq < 4; qq++) {
    int q = tid + qq * 256;
    float sn, cs;
    __sincosf((float)q * 0.003067961575771282f, &sn, &cs);
    float2 v0 = src[PADI(q)];
    float2 v1 = cmul(src[PADI(q + 1024)], make_float2(cs, sn));
    dst[PADI(q)]        = make_float2(v0.x + v1.x, v0.y + v1.y);
    dst[PADI(q + 1024)] = make_float2(v0.x - v1.x, v0.y - v1.y);
  }
}

__global__ __launch_bounds__(256) void k_istft_fused(const float* __restrict__ spec,
        const float* __restrict__ mix, const unsigned int* __restrict__ c2max,
        const float* __restrict__ Rbuf, float* __restrict__ out) {
  __shared__ float2 bufA[2176];
  __shared__ float2 bufB[2176];
  const int tid = threadIdx.x;
  const int u = blockIdx.x % 150;
  const int sid = blockIdx.x / 150;
  const int b = sid >> 3;
  const int s = (sid >> 1) & 3;
  const int ch = sid & 1;
  float acc[16], wsm[16];
#pragma unroll
  for (int k = 0; k < 16; k++) { acc[k] = 0.f; wsm[k] = 0.f; }
  const int t0 = max(0, 4 * u - 1);
  const int t1 = min(TF - 1, 4 * u + 5);
  const int M0 = 2048 + u * 4096;
  for (int t = t0; t <= t1; ++t) {
    for (int k = tid; k < 2048; k += 256) {
      float2 Xa = em_point_one(spec, mix, Rbuf, c2max, b, t, k, s, ch);
      float2 Xb = em_point_one(spec, mix, Rbuf, c2max, b, t, 2048 - k, s, ch);
      if (k == 0) { Xa.y = 0.f; Xb.y = 0.f; }
      float Sx = Xa.x + Xb.x, Sy = Xa.y - Xb.y;
      float Dx = Xa.x - Xb.x, Dy = Xa.y + Xb.y;
      float sn, cs;
      __sincosf((float)k * 0.0015339807878856412f, &sn, &cs);
      bufA[PADI(k)] = make_float2(0.5f * (Sx - sn*Dx - cs*Dy),
                                  0.5f * (Sy + cs*Dx - sn*Dy));
    }
    __syncthreads();
    r4stage<1>(bufA, bufB, tid);   __syncthreads();
    r4stage<4>(bufB, bufA, tid);   __syncthreads();
    r4stage<16>(bufA, bufB, tid);  __syncthreads();
    r4stage<64>(bufB, bufA, tid);  __syncthreads();
    r4stage<256>(bufA, bufB, tid); __syncthreads();
    r2stage(bufB, bufA, tid);      __syncthreads();
    const int delta = M0 - t * HOP;
#pragma unroll
    for (int k2 = 0; k2 < 16; k2++) {
      int n = tid + 256 * k2 + delta;
      if (n >= 0 && n < NFFT) {
        float2 z = bufA[PADI(n >> 1)];
        float xn = (n & 1) ? z.y : z.x;
        float wn = 0.5f - 0.5f * __cosf((float)n * 0.0015339807878856412f);
        acc[k2] += xn * wn * (1.f / 2048.f);
        wsm[k2] += wn * wn;
      }
    }
    __syncthreads();
  }
#pragma unroll
  for (int k2 = 0; k2 < 16; k2++) {
    size_t o = (size_t)u * 4096 + tid + 256 * k2;
    if (o < (size_t)ALEN) {
      float wsv = wsm[k2];
      out[(size_t)sid * ALEN + o] = acc[k2] / (wsv > 1e-11f ? wsv : 1.f);
    }
  }
}

extern "C" void kernel_launch(void* const* d_in, const int* in_sizes, int n_in,
                              void* d_out, int out_size, void* d_ws, size_t ws_size,
                              hipStream_t stream) {
  const float* spec = (const float*)d_in[0];
  const float* mix  = (const float*)d_in[1];
  float* out = (float*)d_out;
  unsigned char* ws = (unsigned char*)d_ws;
  unsigned int* c2max = (unsigned int*)ws;         // 16 B
  float* Rbuf = (float*)(ws + 256);                // 524544 B
  __half2* Y = (__half2*)(ws + 524800);            // 78.7 MB (aliases partials)
  float* part = (float*)(ws + 524800);             // 5.25 MB, consumed before Y written
  const size_t needY = 524800 + (size_t)16 * TF * NB * 4;

  k_init<<<1, 256, 0, stream>>>(c2max);
  k_maxred<<<256, 256, 0, stream>>>(mix, c2max);
  if (ws_size >= needY) {
    k_rmat_part<<<4 * RCH * 9, 256, 0, stream>>>(spec, mix, part);
    k_rmat_red<<<(4 * NB * 4 + 255) / 256, 256, 0, stream>>>(part, c2max, Rbuf);
    int total = 2 * TF * NB;
    k_apply<<<(total + 255) / 256, 256, 0, stream>>>(spec, mix, c2max, Rbuf, Y);
    k_istft_wave<<<16 * 150, 256, 0, stream>>>(Y, out);
  } else {
    k_rmat<<<NB, 256, 0, stream>>>(spec, mix, c2max, Rbuf);
    k_istft_fused<<<16 * 150, 256, 0, stream>>>(spec, mix, c2max, Rbuf, out);
  }
}

// Round 4
// 165.405 us; speedup vs baseline: 2.5077x; 2.5077x over previous
//
#include <hip/hip_runtime.h>
#include <hip/hip_fp16.h>

#define NB 2049
#define TF 600
#define WINF 300
#define NFFT 4096
#define HOP 1024
#define ALEN 613376
#define EPSV 1e-10f
#define SQEPS 1e-5f
#define RCH 10
#define RCHT 30
#define ROWH2 2050            // half2 per Y/frame row (8200 B)
#define W4096 0.0015339807878856412f   /* 2*pi/4096 */

// LDS padding: floor bank distribution for every Stockham access pattern.
#define PADI(i) ((i) + ((i) >> 4))

__device__ __forceinline__ float2 cmul(float2 a, float2 b) {
  return make_float2(a.x*b.x - a.y*b.y, a.x*b.y + a.y*b.x);
}

__device__ __forceinline__ float2 h2f2(unsigned w) {
  union { unsigned u; __half2 h; } c; c.u = w;
  return __half22float2(c.h);
}

__global__ __launch_bounds__(256) void k_init(unsigned int* c2max) {
  if (blockIdx.x == 0 && threadIdx.x < 4) c2max[threadIdx.x] = 0u;
}

// ---- K1: per-window max |mix|^2 -------------------------------------------
__global__ __launch_bounds__(256) void k_maxred(const float* __restrict__ mix,
                                                unsigned int* __restrict__ c2max) {
  int winid = blockIdx.x >> 6;
  int blk = blockIdx.x & 63;
  const float4* p = (const float4*)(mix + (size_t)winid * (WINF * NB * 2 * 2));
  const int n4 = WINF * NB * 2 * 2 / 4;
  float m = 0.f;
  for (int i = blk * 256 + threadIdx.x; i < n4; i += 64 * 256) {
    float4 v = p[i];
    m = fmaxf(m, fmaxf(v.x*v.x + v.y*v.y, v.z*v.z + v.w*v.w));
  }
  for (int off = 32; off; off >>= 1) m = fmaxf(m, __shfl_xor(m, off));
  __shared__ float sm[4];
  if ((threadIdx.x & 63) == 0) sm[threadIdx.x >> 6] = m;
  __syncthreads();
  if (threadIdx.x == 0) {
    m = fmaxf(fmaxf(sm[0], sm[1]), fmaxf(sm[2], sm[3]));
    atomicMax(c2max + winid, __float_as_uint(m));
  }
}

// ---- K2a: covariance partials, lane = f (coalesced) -----------------------
__global__ __launch_bounds__(256) void k_rmat_part(const float* __restrict__ spec,
                                                   const float* __restrict__ mix,
                                                   float* __restrict__ part) {
  int ftile = blockIdx.x % 9;
  int chunk = (blockIdx.x / 9) % RCH;
  int winid = blockIdx.x / (9 * RCH);
  int f = ftile * 256 + threadIdx.x;
  if (f >= NB) return;
  int b = winid >> 1, w = winid & 1;
  float acc[16];
#pragma unroll
  for (int i = 0; i < 16; i++) acc[i] = 0.f;
  for (int tt = 0; tt < RCHT; tt++) {
    int t = w * WINF + chunk * RCHT + tt;
    size_t base = (size_t)(b * TF + t) * NB + f;
    const float4* sp = (const float4*)(spec + base * 8);
    float4 s0 = sp[0], s1 = sp[1];
    float4 mx = *(const float4*)(mix + base * 4);
    float n0 = mx.x*mx.x + mx.y*mx.y;
    float n1 = mx.z*mx.z + mx.w*mx.w;
    float qr, qi;
    if (n0 > 0.f && n1 > 0.f) {
      float inv = rsqrtf(n0 * n1);
      qr = (mx.x*mx.z + mx.y*mx.w) * inv;
      qi = (mx.y*mx.z - mx.x*mx.w) * inv;
    } else if (n0 > 0.f) { float inv = rsqrtf(n0); qr = mx.x*inv; qi = mx.y*inv; }
    else if (n1 > 0.f)   { float inv = rsqrtf(n1); qr = mx.z*inv; qi = -mx.w*inv; }
    else { qr = 1.f; qi = 0.f; }
    float A0[4] = {s0.x, s0.y, s0.z, s0.w};
    float A1[4] = {s1.x, s1.y, s1.z, s1.w};
#pragma unroll
    for (int s = 0; s < 4; s++) {
      acc[s*4+0] += A0[s]*A0[s];
      acc[s*4+1] += A1[s]*A1[s];
      float aa = A0[s]*A1[s];
      acc[s*4+2] += aa * qr;
      acc[s*4+3] += aa * qi;
    }
  }
  float* pp = part + (((size_t)winid * RCH + chunk) * NB + f) * 16;
#pragma unroll
  for (int s = 0; s < 4; s++)
    *(float4*)(pp + s*4) = make_float4(acc[s*4+0], acc[s*4+1], acc[s*4+2], acc[s*4+3]);
}

// ---- K2b: reduce partials + normalize -> Rbuf -----------------------------
__global__ __launch_bounds__(256) void k_rmat_red(const float* __restrict__ part,
                                                  const unsigned int* __restrict__ c2max,
                                                  float* __restrict__ Rbuf) {
  int idx = blockIdx.x * 256 + threadIdx.x;
  if (idx >= 4 * NB * 4) return;
  int s = idx & 3;
  int f = (idx >> 2) % NB;
  int winid = idx / (NB * 4);
  float4 a = make_float4(0.f, 0.f, 0.f, 0.f);
#pragma unroll
  for (int ch = 0; ch < RCH; ch++) {
    float4 p = *(const float4*)(part + (((size_t)winid * RCH + ch) * NB + f) * 16 + s * 4);
    a.x += p.x; a.y += p.y; a.z += p.z; a.w += p.w;
  }
  float c = fmaxf(1.f, sqrtf(__uint_as_float(c2max[winid])) * 0.1f);
  float W = c * c * EPSV + 0.5f * (a.x + a.y);
  float invW = 1.f / W;
  *(float4*)(Rbuf + ((size_t)winid * NB + f) * 16 + s * 4) =
      make_float4(a.x*invW, a.y*invW, a.z*invW, a.w*invW);
}

// ---- legacy K2 (fallback only) --------------------------------------------
__global__ __launch_bounds__(256) void k_rmat(const float* __restrict__ spec,
                                              const float* __restrict__ mix,
                                              const unsigned int* __restrict__ c2max,
                                              float* __restrict__ Rbuf) {
  int f = blockIdx.x;
  int winid = threadIdx.x >> 6;
  int lane = threadIdx.x & 63;
  int b = winid >> 1, w = winid & 1;
  float acc[16];
#pragma unroll
  for (int i = 0; i < 16; i++) acc[i] = 0.f;
  for (int tl = lane; tl < WINF; tl += 64) {
    int t = w * WINF + tl;
    size_t base = (size_t)(b * TF + t) * NB + f;
    const float4* sp = (const float4*)(spec + base * 8);
    float4 s0 = sp[0], s1 = sp[1];
    float4 mx = *(const float4*)(mix + base * 4);
    float n0 = mx.x*mx.x + mx.y*mx.y;
    float n1 = mx.z*mx.z + mx.w*mx.w;
    float qr, qi;
    if (n0 > 0.f && n1 > 0.f) {
      float inv = rsqrtf(n0 * n1);
      qr = (mx.x*mx.z + mx.y*mx.w) * inv;
      qi = (mx.y*mx.z - mx.x*mx.w) * inv;
    } else if (n0 > 0.f) { float inv = rsqrtf(n0); qr = mx.x*inv; qi = mx.y*inv; }
    else if (n1 > 0.f)   { float inv = rsqrtf(n1); qr = mx.z*inv; qi = -mx.w*inv; }
    else { qr = 1.f; qi = 0.f; }
    float A0[4] = {s0.x, s0.y, s0.z, s0.w};
    float A1[4] = {s1.x, s1.y, s1.z, s1.w};
#pragma unroll
    for (int s = 0; s < 4; s++) {
      acc[s*4+0] += A0[s]*A0[s];
      acc[s*4+1] += A1[s]*A1[s];
      float aa = A0[s]*A1[s];
      acc[s*4+2] += aa * qr;
      acc[s*4+3] += aa * qi;
    }
  }
#pragma unroll
  for (int i = 0; i < 16; i++) {
#pragma unroll
    for (int off = 32; off; off >>= 1) acc[i] += __shfl_xor(acc[i], off);
  }
  if (lane == 0) {
    float c = fmaxf(1.f, sqrtf(__uint_as_float(c2max[winid])) * 0.1f);
    float c2 = c * c;
#pragma unroll
    for (int s = 0; s < 4; s++) {
      float W = c2 * EPSV + 0.5f * (acc[s*4+0] + acc[s*4+1]);
      float invW = 1.f / W;
      *(float4*)(Rbuf + ((size_t)winid * NB + f) * 16 + s * 4) =
          make_float4(acc[s*4+0]*invW, acc[s*4+1]*invW, acc[s*4+2]*invW, acc[s*4+3]*invW);
    }
  }
}

// ---- K3: EM apply, write Y (fp16 complex), row stride ROWH2 ---------------
__global__ __launch_bounds__(256) void k_apply(const float* __restrict__ spec,
                                               const float* __restrict__ mix,
                                               const unsigned int* __restrict__ c2max,
                                               const float* __restrict__ Rbuf,
                                               __half2* __restrict__ Y) {
  size_t idx = (size_t)blockIdx.x * 256 + threadIdx.x;
  if (idx >= (size_t)2 * TF * NB) return;
  int f = (int)(idx % NB);
  int r = (int)(idx / NB);
  int t = r % TF, b = r / TF;
  int winid = b * 2 + (t >= WINF ? 1 : 0);
  float c = fmaxf(1.f, sqrtf(__uint_as_float(c2max[winid])) * 0.1f);
  float invc = 1.f / c, inv2c2 = 0.5f * invc * invc;
  size_t base = (size_t)(b * TF + t) * NB + f;
  const float4* sp = (const float4*)(spec + base * 8);
  float4 s0v = sp[0], s1v = sp[1];
  float4 mx = *(const float4*)(mix + base * 4);
  const float4* Rp = (const float4*)(Rbuf + ((size_t)winid * NB + f) * 16);
  float A0[4] = {s0v.x, s0v.y, s0v.z, s0v.w};
  float A1[4] = {s1v.x, s1v.y, s1v.z, s1v.w};
  float v[4]; float4 R[4];
  float C00 = SQEPS, C11 = SQEPS, C01r = 0.f, C01i = 0.f;
#pragma unroll
  for (int sq = 0; sq < 4; sq++) {
    R[sq] = Rp[sq];
    v[sq] = (A0[sq]*A0[sq] + A1[sq]*A1[sq]) * inv2c2;
    C00 += v[sq]*R[sq].x; C11 += v[sq]*R[sq].y;
    C01r += v[sq]*R[sq].z; C01i += v[sq]*R[sq].w;
  }
  float det = C00*C11 - (C01r*C01r + C01i*C01i);
  float invdet = 1.f / det;
  float x0r = mx.x*invc, x0i = mx.y*invc, x1r = mx.z*invc, x1i = mx.w*invc;
  float ix0r = (C11*x0r - (C01r*x1r - C01i*x1i)) * invdet;
  float ix0i = (C11*x0i - (C01r*x1i + C01i*x1r)) * invdet;
  float ix1r = (C00*x1r - (C01r*x0r + C01i*x0i)) * invdet;
  float ix1i = (C00*x1i - (C01r*x0i - C01i*x0r)) * invdet;
#pragma unroll
  for (int sq = 0; sq < 4; sq++) {
    float vc = v[sq] * c;
    float y0r = vc*(R[sq].x*ix0r + R[sq].z*ix1r - R[sq].w*ix1i);
    float y0i = vc*(R[sq].x*ix0i + R[sq].z*ix1i + R[sq].w*ix1r);
    float y1r = vc*(R[sq].z*ix0r + R[sq].w*ix0i + R[sq].y*ix1r);
    float y1i = vc*(R[sq].z*ix0i - R[sq].w*ix0r + R[sq].y*ix1i);
    size_t r0 = ((size_t)(((b * 4 + sq) * 2) * TF) + t) * ROWH2 + f;
    Y[r0] = __floats2half2_rn(y0r, y0i);
    Y[r0 + (size_t)TF * ROWH2] = __floats2half2_rn(y1r, y1i);
  }
}

// ---- FFT stages (inverse Stockham, N=2048), twiddles via __sincosf --------
template<int NS>
__device__ __forceinline__ void r4stage(const float2* __restrict__ src,
                                        float2* __restrict__ dst, int tid) {
#pragma unroll
  for (int qq = 0; qq < 2; qq++) {
    int q = tid + qq * 256;
    int jm = q & (NS - 1);
    float2 v0 = src[PADI(q)];
    float2 v1 = src[PADI(q + 512)];
    float2 v2 = src[PADI(q + 1024)];
    float2 v3 = src[PADI(q + 1536)];
    if constexpr (NS > 1) {
      float sn, cs;
      __sincosf((float)jm * (1.5707963267948966f / (float)NS), &sn, &cs);
      float2 w1 = make_float2(cs, sn);
      float2 w2 = cmul(w1, w1);
      float2 w3 = cmul(w2, w1);
      v1 = cmul(v1, w1);
      v2 = cmul(v2, w2);
      v3 = cmul(v3, w3);
    }
    float2 a0 = make_float2(v0.x + v2.x, v0.y + v2.y);
    float2 a1 = make_float2(v0.x - v2.x, v0.y - v2.y);
    float2 a2 = make_float2(v1.x + v3.x, v1.y + v3.y);
    float2 a3 = make_float2(v1.x - v3.x, v1.y - v3.y);
    int d = ((q - jm) << 2) + jm;
    dst[PADI(d)]        = make_float2(a0.x + a2.x, a0.y + a2.y);
    dst[PADI(d + NS)]   = make_float2(a1.x - a3.y, a1.y + a3.x);
    dst[PADI(d + 2*NS)] = make_float2(a0.x - a2.x, a0.y - a2.y);
    dst[PADI(d + 3*NS)] = make_float2(a1.x + a3.y, a1.y - a3.x);
  }
}

__device__ __forceinline__ void r2stage(const float2* __restrict__ src,
                                        float2* __restrict__ dst, int tid) {
#pragma unroll
  for (int qq = 0; qq < 4; qq++) {
    int q = tid + qq * 256;
    float sn, cs;
    __sincosf((float)q * 0.003067961575771282f, &sn, &cs);
    float2 v0 = src[PADI(q)];
    float2 v1 = cmul(src[PADI(q + 1024)], make_float2(cs, sn));
    dst[PADI(q)]        = make_float2(v0.x + v1.x, v0.y + v1.y);
    dst[PADI(q + 1024)] = make_float2(v0.x - v1.x, v0.y - v1.y);
  }
}

// ---- K4a: one block per (sid, t): irfft + window, overwrite own Y row -----
__global__ __launch_bounds__(256) void k_frames(__half2* __restrict__ YF) {
  __shared__ float2 bufA[2176];
  __shared__ float2 bufB[2176];
  const int tid = threadIdx.x;
  const int t = blockIdx.x % TF;
  const int sid = blockIdx.x / TF;
  const size_t row = ((size_t)sid * TF + t) * ROWH2;

  // stage Y row (2049 half2 words) into LDS
  const unsigned* Yu = (const unsigned*)(YF + row);
  unsigned* stg = (unsigned*)bufB;
  for (int i = tid; i < NB; i += 256) stg[i] = Yu[i];
  __syncthreads();

  // Hermitian fold: Z[k] = Xe + i*Xo
#pragma unroll
  for (int j = 0; j < 8; j++) {
    int k = tid + 256 * j;
    float2 Xa = h2f2(stg[k]);
    float2 Xb = h2f2(stg[2048 - k]);
    if (k == 0) { Xa.y = 0.f; Xb.y = 0.f; }
    float Sx = Xa.x + Xb.x, Sy = Xa.y - Xb.y;
    float Dx = Xa.x - Xb.x, Dy = Xa.y + Xb.y;
    float sn, cs;
    __sincosf((float)k * 0.0015339807878856412f /* pi/2048 */, &sn, &cs);
    bufA[PADI(k)] = make_float2(0.5f * (Sx - sn*Dx - cs*Dy),
                                0.5f * (Sy + cs*Dx - sn*Dy));
  }
  __syncthreads();
  r4stage<1>(bufA, bufB, tid);   __syncthreads();
  r4stage<4>(bufB, bufA, tid);   __syncthreads();
  r4stage<16>(bufA, bufB, tid);  __syncthreads();
  r4stage<64>(bufB, bufA, tid);  __syncthreads();
  r4stage<256>(bufA, bufB, tid); __syncthreads();
  r2stage(bufB, bufA, tid);      __syncthreads();

  // window + scale, store fp16 pairs over the same row
  __half2* frow = YF + row;
#pragma unroll
  for (int q = 0; q < 8; q++) {
    int n2 = tid + 256 * q;
    float2 z = bufA[PADI(n2)];
    float w0 = 0.5f - 0.5f * __cosf((float)(2 * n2) * W4096);
    float w1 = 0.5f - 0.5f * __cosf((float)(2 * n2 + 1) * W4096);
    frow[n2] = __floats2half2_rn(z.x * w0 * (1.f/2048.f), z.y * w1 * (1.f/2048.f));
  }
}

// ---- K4b: gather overlap-add (4 frames) + wsum normalize ------------------
__global__ __launch_bounds__(256) void k_gather(const __half2* __restrict__ frames,
                                                float* __restrict__ out) {
  const int sid = blockIdx.x / 1198;
  const int o2 = (blockIdx.x % 1198) * 256 + threadIdx.x;   // 306688 pairs
  const int n = 2048 + 2 * o2;
  const int tbase = n >> 10;
  float sx = 0.f, sy = 0.f;
#pragma unroll
  for (int dt = 0; dt < 4; dt++) {
    int t = tbase - 3 + dt;
    if ((unsigned)t < (unsigned)TF) {
      int j2 = (n - (t << 10)) >> 1;
      float2 v = __half22float2(frames[((size_t)sid * TF + t) * ROWH2 + j2]);
      sx += v.x; sy += v.y;
    }
  }
  float ise, iso;
  if (tbase >= 3 && tbase <= 599) {
    ise = iso = 2.f / 3.f;   // wsum exactly 1.5 interior
  } else {
    float we = 0.f, wo = 0.f;
#pragma unroll
    for (int dt = 0; dt < 4; dt++) {
      int t = tbase - 3 + dt;
      if ((unsigned)t < (unsigned)TF) {
        int j = n - (t << 10);
        float a = 0.5f - 0.5f * __cosf((float)j * W4096);
        float bq = 0.5f - 0.5f * __cosf((float)(j + 1) * W4096);
        we += a * a; wo += bq * bq;
      }
    }
    ise = 1.f / ((we > 1e-11f) ? we : 1.f);
    iso = 1.f / ((wo > 1e-11f) ? wo : 1.f);
  }
  *(float2*)(out + (size_t)sid * ALEN + 2 * o2) = make_float2(sx * ise, sy * iso);
}

// ---- legacy fused path (fallback if ws too small) -------------------------
__device__ __forceinline__ float2 em_point_one(const float* __restrict__ spec,
    const float* __restrict__ mix, const float* __restrict__ Rbuf,
    const unsigned int* __restrict__ c2max, int b, int t, int f, int ssel, int ch) {
  int winid = b * 2 + (t >= WINF ? 1 : 0);
  float c = fmaxf(1.f, sqrtf(__uint_as_float(c2max[winid])) * 0.1f);
  float invc = 1.f / c, inv2c2 = 0.5f * invc * invc;
  size_t base = (size_t)(b * TF + t) * NB + f;
  const float4* sp = (const float4*)(spec + base * 8);
  float4 s0 = sp[0], s1 = sp[1];
  float4 mx = *(const float4*)(mix + base * 4);
  const float4* Rp = (const float4*)(Rbuf + ((size_t)winid * NB + f) * 16);
  float A0v[4] = {s0.x, s0.y, s0.z, s0.w};
  float A1v[4] = {s1.x, s1.y, s1.z, s1.w};
  float C00 = SQEPS, C11 = SQEPS, C01r = 0.f, C01i = 0.f;
  float vsel = 0.f; float4 Rsel = make_float4(0.f, 0.f, 0.f, 0.f);
#pragma unroll
  for (int sq = 0; sq < 4; sq++) {
    float4 R = Rp[sq];
    float v = (A0v[sq]*A0v[sq] + A1v[sq]*A1v[sq]) * inv2c2;
    C00 += v*R.x; C11 += v*R.y; C01r += v*R.z; C01i += v*R.w;
    if (sq == ssel) { vsel = v; Rsel = R; }
  }
  float det = C00*C11 - (C01r*C01r + C01i*C01i);
  float invdet = 1.f / det;
  float x0r = mx.x*invc, x0i = mx.y*invc, x1r = mx.z*invc, x1i = mx.w*invc;
  float ix0r = (C11*x0r - (C01r*x1r - C01i*x1i)) * invdet;
  float ix0i = (C11*x0i - (C01r*x1i + C01i*x1r)) * invdet;
  float ix1r = (C00*x1r - (C01r*x0r + C01i*x0i)) * invdet;
  float ix1i = (C00*x1i - (C01r*x0i - C01i*x0r)) * invdet;
  float vc = vsel * c;
  if (ch == 0)
    return make_float2(vc*(Rsel.x*ix0r + Rsel.z*ix1r - Rsel.w*ix1i),
                       vc*(Rsel.x*ix0i + Rsel.z*ix1i + Rsel.w*ix1r));
  return make_float2(vc*(Rsel.z*ix0r + Rsel.w*ix0i + Rsel.y*ix1r),
                     vc*(Rsel.z*ix0i - Rsel.w*ix0r + Rsel.y*ix1i));
}

__global__ __launch_bounds__(256) void k_istft_fused(const float* __restrict__ spec,
        const float* __restrict__ mix, const unsigned int* __restrict__ c2max,
        const float* __restrict__ Rbuf, float* __restrict__ out) {
  __shared__ float2 bufA[2176];
  __shared__ float2 bufB[2176];
  const int tid = threadIdx.x;
  const int u = blockIdx.x % 150;
  const int sid = blockIdx.x / 150;
  const int b = sid >> 3;
  const int s = (sid >> 1) & 3;
  const int ch = sid & 1;
  float acc[16], wsm[16];
#pragma unroll
  for (int k = 0; k < 16; k++) { acc[k] = 0.f; wsm[k] = 0.f; }
  const int t0 = max(0, 4 * u - 1);
  const int t1 = min(TF - 1, 4 * u + 5);
  const int M0 = 2048 + u * 4096;
  for (int t = t0; t <= t1; ++t) {
    for (int k = tid; k < 2048; k += 256) {
      float2 Xa = em_point_one(spec, mix, Rbuf, c2max, b, t, k, s, ch);
      float2 Xb = em_point_one(spec, mix, Rbuf, c2max, b, t, 2048 - k, s, ch);
      if (k == 0) { Xa.y = 0.f; Xb.y = 0.f; }
      float Sx = Xa.x + Xb.x, Sy = Xa.y - Xb.y;
      float Dx = Xa.x - Xb.x, Dy = Xa.y + Xb.y;
      float sn, cs;
      __sincosf((float)k * 0.0015339807878856412f, &sn, &cs);
      bufA[PADI(k)] = make_float2(0.5f * (Sx - sn*Dx - cs*Dy),
                                  0.5f * (Sy + cs*Dx - sn*Dy));
    }
    __syncthreads();
    r4stage<1>(bufA, bufB, tid);   __syncthreads();
    r4stage<4>(bufB, bufA, tid);   __syncthreads();
    r4stage<16>(bufA, bufB, tid);  __syncthreads();
    r4stage<64>(bufB, bufA, tid);  __syncthreads();
    r4stage<256>(bufA, bufB, tid); __syncthreads();
    r2stage(bufB, bufA, tid);      __syncthreads();
    const int delta = M0 - t * HOP;
#pragma unroll
    for (int k2 = 0; k2 < 16; k2++) {
      int n = tid + 256 * k2 + delta;
      if (n >= 0 && n < NFFT) {
        float2 z = bufA[PADI(n >> 1)];
        float xn = (n & 1) ? z.y : z.x;
        float wn = 0.5f - 0.5f * __cosf((float)n * W4096);
        acc[k2] += xn * wn * (1.f / 2048.f);
        wsm[k2] += wn * wn;
      }
    }
    __syncthreads();
  }
#pragma unroll
  for (int k2 = 0; k2 < 16; k2++) {
    size_t o = (size_t)u * 4096 + tid + 256 * k2;
    if (o < (size_t)ALEN) {
      float wsv = wsm[k2];
      out[(size_t)sid * ALEN + o] = acc[k2] / (wsv > 1e-11f ? wsv : 1.f);
    }
  }
}

extern "C" void kernel_launch(void* const* d_in, const int* in_sizes, int n_in,
                              void* d_out, int out_size, void* d_ws, size_t ws_size,
                              hipStream_t stream) {
  const float* spec = (const float*)d_in[0];
  const float* mix  = (const float*)d_in[1];
  float* out = (float*)d_out;
  unsigned char* ws = (unsigned char*)d_ws;
  unsigned int* c2max = (unsigned int*)ws;         // 16 B
  float* Rbuf = (float*)(ws + 256);                // 524544 B
  __half2* Y = (__half2*)(ws + 524800);            // 16*600*2050*4 = 78.72 MB
  float* part = (float*)(ws + 524800);             // 5.25 MB, consumed before Y written
  const size_t needY = 524800 + (size_t)16 * TF * ROWH2 * 4;

  k_init<<<1, 256, 0, stream>>>(c2max);
  k_maxred<<<256, 256, 0, stream>>>(mix, c2max);
  if (ws_size >= needY) {
    k_rmat_part<<<4 * RCH * 9, 256, 0, stream>>>(spec, mix, part);
    k_rmat_red<<<(4 * NB * 4 + 255) / 256, 256, 0, stream>>>(part, c2max, Rbuf);
    int total = 2 * TF * NB;
    k_apply<<<(total + 255) / 256, 256, 0, stream>>>(spec, mix, c2max, Rbuf, Y);
    k_frames<<<16 * TF, 256, 0, stream>>>(Y);
    k_gather<<<16 * 1198, 256, 0, stream>>>(Y, out);
  } else {
    k_rmat<<<NB, 256, 0, stream>>>(spec, mix, c2max, Rbuf);
    k_istft_fused<<<16 * 150, 256, 0, stream>>>(spec, mix, c2max, Rbuf, out);
  }
}

// Round 5
// 142.054 us; speedup vs baseline: 2.9199x; 1.1644x over previous
//
#include <hip/hip_runtime.h>
#include <hip/hip_fp16.h>

#define NB 2049
#define TF 600
#define WINF 300
#define NFFT 4096
#define HOP 1024
#define ALEN 613376
#define EPSV 1e-10f
#define SQEPS 1e-5f
#define RCH 10
#define RCHT 30
#define ROWH2 2050            // half2 per Y/frame row (8200 B)
#define W4096 0.0015339807878856412f   /* 2*pi/4096 */

// LDS padding: floor bank distribution for every Stockham access pattern.
#define PADI(i) ((i) + ((i) >> 4))

__device__ __forceinline__ float2 cmul(float2 a, float2 b) {
  return make_float2(a.x*b.x - a.y*b.y, a.x*b.y + a.y*b.x);
}
__device__ __forceinline__ float2 cadd(float2 a, float2 b) {
  return make_float2(a.x + b.x, a.y + b.y);
}
__device__ __forceinline__ float2 csub(float2 a, float2 b) {
  return make_float2(a.x - b.x, a.y - b.y);
}

__device__ __forceinline__ float2 h2f2(unsigned w) {
  union { unsigned u; __half2 h; } c; c.u = w;
  return __half22float2(c.h);
}

__global__ __launch_bounds__(256) void k_init(unsigned int* c2max) {
  if (blockIdx.x == 0 && threadIdx.x < 4) c2max[threadIdx.x] = 0u;
}

// ---- K1 (fallback only): per-window max |mix|^2 ---------------------------
__global__ __launch_bounds__(256) void k_maxred(const float* __restrict__ mix,
                                                unsigned int* __restrict__ c2max) {
  int winid = blockIdx.x >> 6;
  int blk = blockIdx.x & 63;
  const float4* p = (const float4*)(mix + (size_t)winid * (WINF * NB * 2 * 2));
  const int n4 = WINF * NB * 2 * 2 / 4;
  float m = 0.f;
  for (int i = blk * 256 + threadIdx.x; i < n4; i += 64 * 256) {
    float4 v = p[i];
    m = fmaxf(m, fmaxf(v.x*v.x + v.y*v.y, v.z*v.z + v.w*v.w));
  }
  for (int off = 32; off; off >>= 1) m = fmaxf(m, __shfl_xor(m, off));
  __shared__ float sm[4];
  if ((threadIdx.x & 63) == 0) sm[threadIdx.x >> 6] = m;
  __syncthreads();
  if (threadIdx.x == 0) {
    m = fmaxf(fmaxf(sm[0], sm[1]), fmaxf(sm[2], sm[3]));
    atomicMax(c2max + winid, __float_as_uint(m));
  }
}

// ---- K2a: covariance partials, lane = f (coalesced) + fused |mix|^2 max ---
__global__ __launch_bounds__(256) void k_rmat_part(const float* __restrict__ spec,
                                                   const float* __restrict__ mix,
                                                   float* __restrict__ part,
                                                   unsigned int* __restrict__ c2max) {
  int ftile = blockIdx.x % 9;
  int chunk = (blockIdx.x / 9) % RCH;
  int winid = blockIdx.x / (9 * RCH);
  int f = ftile * 256 + threadIdx.x;
  const bool act = (f < NB);
  int b = winid >> 1, w = winid & 1;
  float acc[16];
#pragma unroll
  for (int i = 0; i < 16; i++) acc[i] = 0.f;
  float mx2 = 0.f;
  if (act) {
    for (int tt = 0; tt < RCHT; tt++) {
      int t = w * WINF + chunk * RCHT + tt;
      size_t base = (size_t)(b * TF + t) * NB + f;
      const float4* sp = (const float4*)(spec + base * 8);
      float4 s0 = sp[0], s1 = sp[1];
      float4 mx = *(const float4*)(mix + base * 4);
      float n0 = mx.x*mx.x + mx.y*mx.y;
      float n1 = mx.z*mx.z + mx.w*mx.w;
      mx2 = fmaxf(mx2, fmaxf(n0, n1));
      float qr, qi;
      if (n0 > 0.f && n1 > 0.f) {
        float inv = rsqrtf(n0 * n1);
        qr = (mx.x*mx.z + mx.y*mx.w) * inv;
        qi = (mx.y*mx.z - mx.x*mx.w) * inv;
      } else if (n0 > 0.f) { float inv = rsqrtf(n0); qr = mx.x*inv; qi = mx.y*inv; }
      else if (n1 > 0.f)   { float inv = rsqrtf(n1); qr = mx.z*inv; qi = -mx.w*inv; }
      else { qr = 1.f; qi = 0.f; }
      float A0[4] = {s0.x, s0.y, s0.z, s0.w};
      float A1[4] = {s1.x, s1.y, s1.z, s1.w};
#pragma unroll
      for (int s = 0; s < 4; s++) {
        acc[s*4+0] += A0[s]*A0[s];
        acc[s*4+1] += A1[s]*A1[s];
        float aa = A0[s]*A1[s];
        acc[s*4+2] += aa * qr;
        acc[s*4+3] += aa * qi;
      }
    }
    float* pp = part + (((size_t)winid * RCH + chunk) * NB + f) * 16;
#pragma unroll
    for (int s = 0; s < 4; s++)
      *(float4*)(pp + s*4) = make_float4(acc[s*4+0], acc[s*4+1], acc[s*4+2], acc[s*4+3]);
  }
  // block-level max -> atomicMax (all threads participate)
  for (int off = 32; off; off >>= 1) mx2 = fmaxf(mx2, __shfl_xor(mx2, off));
  __shared__ float sm[4];
  if ((threadIdx.x & 63) == 0) sm[threadIdx.x >> 6] = mx2;
  __syncthreads();
  if (threadIdx.x == 0) {
    mx2 = fmaxf(fmaxf(sm[0], sm[1]), fmaxf(sm[2], sm[3]));
    atomicMax(c2max + winid, __float_as_uint(mx2));
  }
}

// ---- K2b: reduce partials + normalize -> Rbuf -----------------------------
__global__ __launch_bounds__(256) void k_rmat_red(const float* __restrict__ part,
                                                  const unsigned int* __restrict__ c2max,
                                                  float* __restrict__ Rbuf) {
  int idx = blockIdx.x * 256 + threadIdx.x;
  if (idx >= 4 * NB * 4) return;
  int s = idx & 3;
  int f = (idx >> 2) % NB;
  int winid = idx / (NB * 4);
  float4 a = make_float4(0.f, 0.f, 0.f, 0.f);
#pragma unroll
  for (int ch = 0; ch < RCH; ch++) {
    float4 p = *(const float4*)(part + (((size_t)winid * RCH + ch) * NB + f) * 16 + s * 4);
    a.x += p.x; a.y += p.y; a.z += p.z; a.w += p.w;
  }
  float c = fmaxf(1.f, sqrtf(__uint_as_float(c2max[winid])) * 0.1f);
  float W = c * c * EPSV + 0.5f * (a.x + a.y);
  float invW = 1.f / W;
  *(float4*)(Rbuf + ((size_t)winid * NB + f) * 16 + s * 4) =
      make_float4(a.x*invW, a.y*invW, a.z*invW, a.w*invW);
}

// ---- legacy K2 (fallback only) --------------------------------------------
__global__ __launch_bounds__(256) void k_rmat(const float* __restrict__ spec,
                                              const float* __restrict__ mix,
                                              const unsigned int* __restrict__ c2max,
                                              float* __restrict__ Rbuf) {
  int f = blockIdx.x;
  int winid = threadIdx.x >> 6;
  int lane = threadIdx.x & 63;
  int b = winid >> 1, w = winid & 1;
  float acc[16];
#pragma unroll
  for (int i = 0; i < 16; i++) acc[i] = 0.f;
  for (int tl = lane; tl < WINF; tl += 64) {
    int t = w * WINF + tl;
    size_t base = (size_t)(b * TF + t) * NB + f;
    const float4* sp = (const float4*)(spec + base * 8);
    float4 s0 = sp[0], s1 = sp[1];
    float4 mx = *(const float4*)(mix + base * 4);
    float n0 = mx.x*mx.x + mx.y*mx.y;
    float n1 = mx.z*mx.z + mx.w*mx.w;
    float qr, qi;
    if (n0 > 0.f && n1 > 0.f) {
      float inv = rsqrtf(n0 * n1);
      qr = (mx.x*mx.z + mx.y*mx.w) * inv;
      qi = (mx.y*mx.z - mx.x*mx.w) * inv;
    } else if (n0 > 0.f) { float inv = rsqrtf(n0); qr = mx.x*inv; qi = mx.y*inv; }
    else if (n1 > 0.f)   { float inv = rsqrtf(n1); qr = mx.z*inv; qi = -mx.w*inv; }
    else { qr = 1.f; qi = 0.f; }
    float A0[4] = {s0.x, s0.y, s0.z, s0.w};
    float A1[4] = {s1.x, s1.y, s1.z, s1.w};
#pragma unroll
    for (int s = 0; s < 4; s++) {
      acc[s*4+0] += A0[s]*A0[s];
      acc[s*4+1] += A1[s]*A1[s];
      float aa = A0[s]*A1[s];
      acc[s*4+2] += aa * qr;
      acc[s*4+3] += aa * qi;
    }
  }
#pragma unroll
  for (int i = 0; i < 16; i++) {
#pragma unroll
    for (int off = 32; off; off >>= 1) acc[i] += __shfl_xor(acc[i], off);
  }
  if (lane == 0) {
    float c = fmaxf(1.f, sqrtf(__uint_as_float(c2max[winid])) * 0.1f);
    float c2 = c * c;
#pragma unroll
    for (int s = 0; s < 4; s++) {
      float W = c2 * EPSV + 0.5f * (acc[s*4+0] + acc[s*4+1]);
      float invW = 1.f / W;
      *(float4*)(Rbuf + ((size_t)winid * NB + f) * 16 + s * 4) =
          make_float4(acc[s*4+0]*invW, acc[s*4+1]*invW, acc[s*4+2]*invW, acc[s*4+3]*invW);
    }
  }
}

// ---- K3: EM apply, write Y (fp16 complex), row stride ROWH2 ---------------
__global__ __launch_bounds__(256) void k_apply(const float* __restrict__ spec,
                                               const float* __restrict__ mix,
                                               const unsigned int* __restrict__ c2max,
                                               const float* __restrict__ Rbuf,
                                               __half2* __restrict__ Y) {
  size_t idx = (size_t)blockIdx.x * 256 + threadIdx.x;
  if (idx >= (size_t)2 * TF * NB) return;
  int f = (int)(idx % NB);
  int r = (int)(idx / NB);
  int t = r % TF, b = r / TF;
  int winid = b * 2 + (t >= WINF ? 1 : 0);
  float c = fmaxf(1.f, sqrtf(__uint_as_float(c2max[winid])) * 0.1f);
  float invc = 1.f / c, inv2c2 = 0.5f * invc * invc;
  size_t base = (size_t)(b * TF + t) * NB + f;
  const float4* sp = (const float4*)(spec + base * 8);
  float4 s0v = sp[0], s1v = sp[1];
  float4 mx = *(const float4*)(mix + base * 4);
  const float4* Rp = (const float4*)(Rbuf + ((size_t)winid * NB + f) * 16);
  float A0[4] = {s0v.x, s0v.y, s0v.z, s0v.w};
  float A1[4] = {s1v.x, s1v.y, s1v.z, s1v.w};
  float v[4]; float4 R[4];
  float C00 = SQEPS, C11 = SQEPS, C01r = 0.f, C01i = 0.f;
#pragma unroll
  for (int sq = 0; sq < 4; sq++) {
    R[sq] = Rp[sq];
    v[sq] = (A0[sq]*A0[sq] + A1[sq]*A1[sq]) * inv2c2;
    C00 += v[sq]*R[sq].x; C11 += v[sq]*R[sq].y;
    C01r += v[sq]*R[sq].z; C01i += v[sq]*R[sq].w;
  }
  float det = C00*C11 - (C01r*C01r + C01i*C01i);
  float invdet = 1.f / det;
  float x0r = mx.x*invc, x0i = mx.y*invc, x1r = mx.z*invc, x1i = mx.w*invc;
  float ix0r = (C11*x0r - (C01r*x1r - C01i*x1i)) * invdet;
  float ix0i = (C11*x0i - (C01r*x1i + C01i*x1r)) * invdet;
  float ix1r = (C00*x1r - (C01r*x0r + C01i*x0i)) * invdet;
  float ix1i = (C00*x1i - (C01r*x0i - C01i*x0r)) * invdet;
#pragma unroll
  for (int sq = 0; sq < 4; sq++) {
    float vc = v[sq] * c;
    float y0r = vc*(R[sq].x*ix0r + R[sq].z*ix1r - R[sq].w*ix1i);
    float y0i = vc*(R[sq].x*ix0i + R[sq].z*ix1i + R[sq].w*ix1r);
    float y1r = vc*(R[sq].z*ix0r + R[sq].w*ix0i + R[sq].y*ix1r);
    float y1i = vc*(R[sq].z*ix0i - R[sq].w*ix0r + R[sq].y*ix1i);
    size_t r0 = ((size_t)(((b * 4 + sq) * 2) * TF) + t) * ROWH2 + f;
    Y[r0] = __floats2half2_rn(y0r, y0i);
    Y[r0 + (size_t)TF * ROWH2] = __floats2half2_rn(y1r, y1i);
  }
}

// ---- inverse DFT-8 (unnormalized, e^{+i}) ---------------------------------
__device__ __forceinline__ void dft8(const float2* x, float2* X) {
  const float S2 = 0.70710678118654752f;
  float2 t0 = cadd(x[0], x[4]), t1 = csub(x[0], x[4]);
  float2 t2 = cadd(x[2], x[6]), t3 = csub(x[2], x[6]);
  float2 E0 = cadd(t0, t2), E2 = csub(t0, t2);
  float2 E1 = make_float2(t1.x - t3.y, t1.y + t3.x);
  float2 E3 = make_float2(t1.x + t3.y, t1.y - t3.x);
  float2 u0 = cadd(x[1], x[5]), u1 = csub(x[1], x[5]);
  float2 u2 = cadd(x[3], x[7]), u3 = csub(x[3], x[7]);
  float2 O0 = cadd(u0, u2), O2 = csub(u0, u2);
  float2 O1 = make_float2(u1.x - u3.y, u1.y + u3.x);
  float2 O3 = make_float2(u1.x + u3.y, u1.y - u3.x);
  float2 R1 = make_float2(S2*(O1.x - O1.y), S2*(O1.x + O1.y));   // e^{i pi/4} O1
  float2 R2 = make_float2(-O2.y, O2.x);                          // i O2
  float2 R3 = make_float2(-S2*(O3.x + O3.y), S2*(O3.x - O3.y));  // e^{i 3pi/4} O3
  X[0] = cadd(E0, O0); X[4] = csub(E0, O0);
  X[1] = cadd(E1, R1); X[5] = csub(E1, R1);
  X[2] = cadd(E2, R2); X[6] = csub(E2, R2);
  X[3] = cadd(E3, R3); X[7] = csub(E3, R3);
}

// radix-8 Stockham stage from registers, NS=1 (no twiddles)
__device__ __forceinline__ void r8_reg(const float2* x, float2* dst, int tid) {
  float2 X[8];
  dft8(x, X);
  const int d = tid << 3;
#pragma unroll
  for (int n = 0; n < 8; n++) dst[PADI(d + n)] = X[n];
}

// radix-8 Stockham stage LDS->LDS (256 threads, one butterfly each)
template<int NS>
__device__ __forceinline__ void r8stage(const float2* __restrict__ src,
                                        float2* __restrict__ dst, int tid) {
  const int q = tid;
  const int jm = q & (NS - 1);
  float2 x[8];
#pragma unroll
  for (int m = 0; m < 8; m++) x[m] = src[PADI(q + (m << 8))];
  {
    float sn, cs;
    __sincosf((float)jm * (0.78539816339744831f / (float)NS), &sn, &cs); // 2pi/(8NS)
    const float2 w = make_float2(cs, sn);
    float2 wp = w;
    x[1] = cmul(x[1], wp);
#pragma unroll
    for (int m = 2; m < 8; m++) { wp = cmul(wp, w); x[m] = cmul(x[m], wp); }
  }
  float2 X[8];
  dft8(x, X);
  const int d = ((q - jm) << 3) + jm;
#pragma unroll
  for (int n = 0; n < 8; n++) dst[PADI(d + n * NS)] = X[n];
}

// final radix-4 stage (NS=512) + Hann window + fp16 store (registers only)
__device__ __forceinline__ void r4_final(const float2* __restrict__ src,
                                         __half2* __restrict__ frow, int tid) {
  const float S2 = 0.70710678118654752f;
  // window weights (x 1/2048) for n2 = tid + 256*m, m=0..7; chained rotation pi/4
  float we[8], wo[8];
  float bsn, bcs;
  __sincosf((float)tid * 0.0030679615757712823f /* pi/1024 == 2pi/2048 */, &bsn, &bcs);
  {
    float cs = bcs, sn = bsn;
    const float CD = 0.9999988234517019f, SD = 0.0015339801862847657f; // 2pi/4096
#pragma unroll
    for (int m = 0; m < 8; m++) {
      we[m] = (0.5f - 0.5f*cs) * (1.f/2048.f);
      float c1 = cs*CD - sn*SD;
      wo[m] = (0.5f - 0.5f*c1) * (1.f/2048.f);
      float ncs = (cs - sn) * S2;
      float nsn = (sn + cs) * S2;
      cs = ncs; sn = nsn;
    }
  }
  float2 w1 = make_float2(bcs, bsn);   // e^{i q pi/1024}, q=tid
#pragma unroll
  for (int qq = 0; qq < 2; qq++) {
    const int q = tid + (qq << 8);
    float2 v0 = src[PADI(q)];
    float2 v1 = src[PADI(q + 512)];
    float2 v2 = src[PADI(q + 1024)];
    float2 v3 = src[PADI(q + 1536)];
    float2 w2 = cmul(w1, w1);
    float2 w3 = cmul(w2, w1);
    v1 = cmul(v1, w1);
    v2 = cmul(v2, w2);
    v3 = cmul(v3, w3);
    float2 t0 = cadd(v0, v2), t1 = csub(v0, v2);
    float2 t2 = cadd(v1, v3), t3 = csub(v1, v3);
    float2 X0 = cadd(t0, t2);
    float2 X1 = make_float2(t1.x - t3.y, t1.y + t3.x);
    float2 X2 = csub(t0, t2);
    float2 X3 = make_float2(t1.x + t3.y, t1.y - t3.x);
    frow[q]        = __floats2half2_rn(X0.x*we[qq],     X0.y*wo[qq]);
    frow[q + 512]  = __floats2half2_rn(X1.x*we[qq + 2], X1.y*wo[qq + 2]);
    frow[q + 1024] = __floats2half2_rn(X2.x*we[qq + 4], X2.y*wo[qq + 4]);
    frow[q + 1536] = __floats2half2_rn(X3.x*we[qq + 6], X3.y*wo[qq + 6]);
    if (qq == 0)
      w1 = make_float2((w1.x - w1.y) * S2, (w1.y + w1.x) * S2); // *= e^{i pi/4}
  }
}

// ---- K4a: one block per (sid, t): irfft (radix 8,8,8,4) + window, in place -
__global__ __launch_bounds__(256) void k_frames(__half2* __restrict__ YF) {
  __shared__ float2 bufA[2176];
  __shared__ float2 bufB[2176];
  const int tid = threadIdx.x;
  const int t = blockIdx.x % TF;
  const int sid = blockIdx.x / TF;
  const size_t row = ((size_t)sid * TF + t) * ROWH2;

  // stage Y row (2049 half2 words) into LDS (raw u32 in bufB)
  const unsigned* Yu = (const unsigned*)(YF + row);
  unsigned* stg = (unsigned*)bufB;
  for (int i = tid; i < NB; i += 256) stg[i] = Yu[i];
  __syncthreads();

  // Hermitian fold straight into registers: x[m] = Z[tid + 256m]
  float2 x[8];
  {
    float sn, cs;
    __sincosf((float)tid * 0.0015339807878856412f /* pi/2048 */, &sn, &cs);
    const float R8c = 0.92387953251128676f, R8s = 0.38268343236508977f; // pi/8
#pragma unroll
    for (int m = 0; m < 8; m++) {
      const int k = tid + (m << 8);
      float2 Xa = h2f2(stg[k]);
      float2 Xb = h2f2(stg[2048 - k]);
      if (k == 0) { Xa.y = 0.f; Xb.y = 0.f; }
      float Sx = Xa.x + Xb.x, Sy = Xa.y - Xb.y;
      float Dx = Xa.x - Xb.x, Dy = Xa.y + Xb.y;
      x[m] = make_float2(0.5f*(Sx - sn*Dx - cs*Dy), 0.5f*(Sy + cs*Dx - sn*Dy));
      float ncs = cs*R8c - sn*R8s, nsn = sn*R8c + cs*R8s;
      cs = ncs; sn = nsn;
    }
  }
  r8_reg(x, bufA, tid);     // NS=1 (reads regs, writes bufA; stg in bufB safe)
  __syncthreads();
  r8stage<8>(bufA, bufB, tid);
  __syncthreads();
  r8stage<64>(bufB, bufA, tid);
  __syncthreads();
  r4_final(bufA, YF + row, tid);   // NS=512 + window + store
}

// ---- K4b: gather overlap-add (4 frames) + wsum normalize ------------------
__global__ __launch_bounds__(256) void k_gather(const __half2* __restrict__ frames,
                                                float* __restrict__ out) {
  const int sid = blockIdx.x / 1198;
  const int o2 = (blockIdx.x % 1198) * 256 + threadIdx.x;   // 306688 pairs
  const int n = 2048 + 2 * o2;
  const int tbase = n >> 10;
  float sx = 0.f, sy = 0.f;
#pragma unroll
  for (int dt = 0; dt < 4; dt++) {
    int t = tbase - 3 + dt;
    if ((unsigned)t < (unsigned)TF) {
      int j2 = (n - (t << 10)) >> 1;
      float2 v = __half22float2(frames[((size_t)sid * TF + t) * ROWH2 + j2]);
      sx += v.x; sy += v.y;
    }
  }
  float ise, iso;
  if (tbase >= 3 && tbase <= 599) {
    ise = iso = 2.f / 3.f;   // wsum exactly 1.5 interior
  } else {
    float we = 0.f, wo = 0.f;
#pragma unroll
    for (int dt = 0; dt < 4; dt++) {
      int t = tbase - 3 + dt;
      if ((unsigned)t < (unsigned)TF) {
        int j = n - (t << 10);
        float a = 0.5f - 0.5f * __cosf((float)j * W4096);
        float bq = 0.5f - 0.5f * __cosf((float)(j + 1) * W4096);
        we += a * a; wo += bq * bq;
      }
    }
    ise = 1.f / ((we > 1e-11f) ? we : 1.f);
    iso = 1.f / ((wo > 1e-11f) ? wo : 1.f);
  }
  *(float2*)(out + (size_t)sid * ALEN + 2 * o2) = make_float2(sx * ise, sy * iso);
}

// ---- legacy fused path (fallback if ws too small) -------------------------
__device__ __forceinline__ float2 em_point_one(const float* __restrict__ spec,
    const float* __restrict__ mix, const float* __restrict__ Rbuf,
    const unsigned int* __restrict__ c2max, int b, int t, int f, int ssel, int ch) {
  int winid = b * 2 + (t >= WINF ? 1 : 0);
  float c = fmaxf(1.f, sqrtf(__uint_as_float(c2max[winid])) * 0.1f);
  float invc = 1.f / c, inv2c2 = 0.5f * invc * invc;
  size_t base = (size_t)(b * TF + t) * NB + f;
  const float4* sp = (const float4*)(spec + base * 8);
  float4 s0 = sp[0], s1 = sp[1];
  float4 mx = *(const float4*)(mix + base * 4);
  const float4* Rp = (const float4*)(Rbuf + ((size_t)winid * NB + f) * 16);
  float A0v[4] = {s0.x, s0.y, s0.z, s0.w};
  float A1v[4] = {s1.x, s1.y, s1.z, s1.w};
  float C00 = SQEPS, C11 = SQEPS, C01r = 0.f, C01i = 0.f;
  float vsel = 0.f; float4 Rsel = make_float4(0.f, 0.f, 0.f, 0.f);
#pragma unroll
  for (int sq = 0; sq < 4; sq++) {
    float4 R = Rp[sq];
    float v = (A0v[sq]*A0v[sq] + A1v[sq]*A1v[sq]) * inv2c2;
    C00 += v*R.x; C11 += v*R.y; C01r += v*R.z; C01i += v*R.w;
    if (sq == ssel) { vsel = v; Rsel = R; }
  }
  float det = C00*C11 - (C01r*C01r + C01i*C01i);
  float invdet = 1.f / det;
  float x0r = mx.x*invc, x0i = mx.y*invc, x1r = mx.z*invc, x1i = mx.w*invc;
  float ix0r = (C11*x0r - (C01r*x1r - C01i*x1i)) * invdet;
  float ix0i = (C11*x0i - (C01r*x1i + C01i*x1r)) * invdet;
  float ix1r = (C00*x1r - (C01r*x0r + C01i*x0i)) * invdet;
  float ix1i = (C00*x1i - (C01r*x0i - C01i*x0r)) * invdet;
  float vc = vsel * c;
  if (ch == 0)
    return make_float2(vc*(Rsel.x*ix0r + Rsel.z*ix1r - Rsel.w*ix1i),
                       vc*(Rsel.x*ix0i + Rsel.z*ix1i + Rsel.w*ix1r));
  return make_float2(vc*(Rsel.z*ix0r + Rsel.w*ix0i + Rsel.y*ix1r),
                     vc*(Rsel.z*ix0i - Rsel.w*ix0r + Rsel.y*ix1i));
}

template<int NS>
__device__ __forceinline__ void r4stage(const float2* __restrict__ src,
                                        float2* __restrict__ dst, int tid) {
#pragma unroll
  for (int qq = 0; qq < 2; qq++) {
    int q = tid + qq * 256;
    int jm = q & (NS - 1);
    float2 v0 = src[PADI(q)];
    float2 v1 = src[PADI(q + 512)];
    float2 v2 = src[PADI(q + 1024)];
    float2 v3 = src[PADI(q + 1536)];
    if constexpr (NS > 1) {
      float sn, cs;
      __sincosf((float)jm * (1.5707963267948966f / (float)NS), &sn, &cs);
      float2 w1 = make_float2(cs, sn);
      float2 w2 = cmul(w1, w1);
      float2 w3 = cmul(w2, w1);
      v1 = cmul(v1, w1);
      v2 = cmul(v2, w2);
      v3 = cmul(v3, w3);
    }
    float2 a0 = cadd(v0, v2), a1 = csub(v0, v2);
    float2 a2 = cadd(v1, v3), a3 = csub(v1, v3);
    int d = ((q - jm) << 2) + jm;
    dst[PADI(d)]        = cadd(a0, a2);
    dst[PADI(d + NS)]   = make_float2(a1.x - a3.y, a1.y + a3.x);
    dst[PADI(d + 2*NS)] = csub(a0, a2);
    dst[PADI(d + 3*NS)] = make_float2(a1.x + a3.y, a1.y - a3.x);
  }
}

__device__ __forceinline__ void r2stage(const float2* __restrict__ src,
                                        float2* __restrict__ dst, int tid) {
#pragma unroll
  for (int qq = 0; qq < 4; qq++) {
    int q = tid + qq * 256;
    float sn, cs;
    __sincosf((float)q * 0.003067961575771282f, &sn, &cs);
    float2 v0 = src[PADI(q)];
    float2 v1 = cmul(src[PADI(q + 1024)], make_float2(cs, sn));
    dst[PADI(q)]        = cadd(v0, v1);
    dst[PADI(q + 1024)] = csub(v0, v1);
  }
}

__global__ __launch_bounds__(256) void k_istft_fused(const float* __restrict__ spec,
        const float* __restrict__ mix, const unsigned int* __restrict__ c2max,
        const float* __restrict__ Rbuf, float* __restrict__ out) {
  __shared__ float2 bufA[2176];
  __shared__ float2 bufB[2176];
  const int tid = threadIdx.x;
  const int u = blockIdx.x % 150;
  const int sid = blockIdx.x / 150;
  const int b = sid >> 3;
  const int s = (sid >> 1) & 3;
  const int ch = sid & 1;
  float acc[16], wsm[16];
#pragma unroll
  for (int k = 0; k < 16; k++) { acc[k] = 0.f; wsm[k] = 0.f; }
  const int t0 = max(0, 4 * u - 1);
  const int t1 = min(TF - 1, 4 * u + 5);
  const int M0 = 2048 + u * 4096;
  for (int t = t0; t <= t1; ++t) {
    for (int k = tid; k < 2048; k += 256) {
      float2 Xa = em_point_one(spec, mix, Rbuf, c2max, b, t, k, s, ch);
      float2 Xb = em_point_one(spec, mix, Rbuf, c2max, b, t, 2048 - k, s, ch);
      if (k == 0) { Xa.y = 0.f; Xb.y = 0.f; }
      float Sx = Xa.x + Xb.x, Sy = Xa.y - Xb.y;
      float Dx = Xa.x - Xb.x, Dy = Xa.y + Xb.y;
      float sn, cs;
      __sincosf((float)k * 0.0015339807878856412f, &sn, &cs);
      bufA[PADI(k)] = make_float2(0.5f * (Sx - sn*Dx - cs*Dy),
                                  0.5f * (Sy + cs*Dx - sn*Dy));
    }
    __syncthreads();
    r4stage<1>(bufA, bufB, tid);   __syncthreads();
    r4stage<4>(bufB, bufA, tid);   __syncthreads();
    r4stage<16>(bufA, bufB, tid);  __syncthreads();
    r4stage<64>(bufB, bufA, tid);  __syncthreads();
    r4stage<256>(bufA, bufB, tid); __syncthreads();
    r2stage(bufB, bufA, tid);      __syncthreads();
    const int delta = M0 - t * HOP;
#pragma unroll
    for (int k2 = 0; k2 < 16; k2++) {
      int n = tid + 256 * k2 + delta;
      if (n >= 0 && n < NFFT) {
        float2 z = bufA[PADI(n >> 1)];
        float xn = (n & 1) ? z.y : z.x;
        float wn = 0.5f - 0.5f * __cosf((float)n * W4096);
        acc[k2] += xn * wn * (1.f / 2048.f);
        wsm[k2] += wn * wn;
      }
    }
    __syncthreads();
  }
#pragma unroll
  for (int k2 = 0; k2 < 16; k2++) {
    size_t o = (size_t)u * 4096 + tid + 256 * k2;
    if (o < (size_t)ALEN) {
      float wsv = wsm[k2];
      out[(size_t)sid * ALEN + o] = acc[k2] / (wsv > 1e-11f ? wsv : 1.f);
    }
  }
}

extern "C" void kernel_launch(void* const* d_in, const int* in_sizes, int n_in,
                              void* d_out, int out_size, void* d_ws, size_t ws_size,
                              hipStream_t stream) {
  const float* spec = (const float*)d_in[0];
  const float* mix  = (const float*)d_in[1];
  float* out = (float*)d_out;
  unsigned char* ws = (unsigned char*)d_ws;
  unsigned int* c2max = (unsigned int*)ws;         // 16 B
  float* Rbuf = (float*)(ws + 256);                // 524544 B
  __half2* Y = (__half2*)(ws + 524800);            // 16*600*2050*4 = 78.72 MB
  float* part = (float*)(ws + 524800);             // 5.25 MB, consumed before Y written
  const size_t needY = 524800 + (size_t)16 * TF * ROWH2 * 4;

  k_init<<<1, 256, 0, stream>>>(c2max);
  if (ws_size >= needY) {
    k_rmat_part<<<4 * RCH * 9, 256, 0, stream>>>(spec, mix, part, c2max);
    k_rmat_red<<<(4 * NB * 4 + 255) / 256, 256, 0, stream>>>(part, c2max, Rbuf);
    int total = 2 * TF * NB;
    k_apply<<<(total + 255) / 256, 256, 0, stream>>>(spec, mix, c2max, Rbuf, Y);
    k_frames<<<16 * TF, 256, 0, stream>>>(Y);
    k_gather<<<16 * 1198, 256, 0, stream>>>(Y, out);
  } else {
    k_maxred<<<256, 256, 0, stream>>>(mix, c2max);
    k_rmat<<<NB, 256, 0, stream>>>(spec, mix, c2max, Rbuf);
    k_istft_fused<<<16 * 150, 256, 0, stream>>>(spec, mix, c2max, Rbuf, out);
  }
}

// Round 6
// 137.772 us; speedup vs baseline: 3.0107x; 1.0311x over previous
//
#include <hip/hip_runtime.h>
#include <hip/hip_fp16.h>

#define NB 2049
#define TF 600
#define WINF 300
#define NFFT 4096
#define HOP 1024
#define ALEN 613376
#define EPSV 1e-10f
#define SQEPS 1e-5f
#define RCH 20
#define RCHT 15
#define ROWH2 2050            // half2 per Y/frame row (8200 B)
#define W4096 0.0015339807878856412f   /* 2*pi/4096 */

// LDS padding: floor bank distribution for every Stockham access pattern.
#define PADI(i) ((i) + ((i) >> 4))

__device__ __forceinline__ float2 cmul(float2 a, float2 b) {
  return make_float2(a.x*b.x - a.y*b.y, a.x*b.y + a.y*b.x);
}
__device__ __forceinline__ float2 cadd(float2 a, float2 b) {
  return make_float2(a.x + b.x, a.y + b.y);
}
__device__ __forceinline__ float2 csub(float2 a, float2 b) {
  return make_float2(a.x - b.x, a.y - b.y);
}

__device__ __forceinline__ float2 h2f2(unsigned w) {
  union { unsigned u; __half2 h; } c; c.u = w;
  return __half22float2(c.h);
}

__global__ __launch_bounds__(256) void k_init(unsigned int* c2max) {
  if (blockIdx.x == 0 && threadIdx.x < 4) c2max[threadIdx.x] = 0u;
}

// ---- K1 (fallback only): per-window max |mix|^2 ---------------------------
__global__ __launch_bounds__(256) void k_maxred(const float* __restrict__ mix,
                                                unsigned int* __restrict__ c2max) {
  int winid = blockIdx.x >> 6;
  int blk = blockIdx.x & 63;
  const float4* p = (const float4*)(mix + (size_t)winid * (WINF * NB * 2 * 2));
  const int n4 = WINF * NB * 2 * 2 / 4;
  float m = 0.f;
  for (int i = blk * 256 + threadIdx.x; i < n4; i += 64 * 256) {
    float4 v = p[i];
    m = fmaxf(m, fmaxf(v.x*v.x + v.y*v.y, v.z*v.z + v.w*v.w));
  }
  for (int off = 32; off; off >>= 1) m = fmaxf(m, __shfl_xor(m, off));
  __shared__ float sm[4];
  if ((threadIdx.x & 63) == 0) sm[threadIdx.x >> 6] = m;
  __syncthreads();
  if (threadIdx.x == 0) {
    m = fmaxf(fmaxf(sm[0], sm[1]), fmaxf(sm[2], sm[3]));
    atomicMax(c2max + winid, __float_as_uint(m));
  }
}

// ---- K2a: covariance partials, lane = f (coalesced) + fused |mix|^2 max ---
__global__ __launch_bounds__(256) void k_rmat_part(const float* __restrict__ spec,
                                                   const float* __restrict__ mix,
                                                   float* __restrict__ part,
                                                   unsigned int* __restrict__ c2max) {
  int ftile = blockIdx.x % 9;
  int chunk = (blockIdx.x / 9) % RCH;
  int winid = blockIdx.x / (9 * RCH);
  int f = ftile * 256 + threadIdx.x;
  const bool act = (f < NB);
  int b = winid >> 1, w = winid & 1;
  float acc[16];
#pragma unroll
  for (int i = 0; i < 16; i++) acc[i] = 0.f;
  float mx2 = 0.f;
  if (act) {
    for (int tt = 0; tt < RCHT; tt++) {
      int t = w * WINF + chunk * RCHT + tt;
      size_t base = (size_t)(b * TF + t) * NB + f;
      const float4* sp = (const float4*)(spec + base * 8);
      float4 s0 = sp[0], s1 = sp[1];
      float4 mx = *(const float4*)(mix + base * 4);
      float n0 = mx.x*mx.x + mx.y*mx.y;
      float n1 = mx.z*mx.z + mx.w*mx.w;
      mx2 = fmaxf(mx2, fmaxf(n0, n1));
      float qr, qi;
      if (n0 > 0.f && n1 > 0.f) {
        float inv = rsqrtf(n0 * n1);
        qr = (mx.x*mx.z + mx.y*mx.w) * inv;
        qi = (mx.y*mx.z - mx.x*mx.w) * inv;
      } else if (n0 > 0.f) { float inv = rsqrtf(n0); qr = mx.x*inv; qi = mx.y*inv; }
      else if (n1 > 0.f)   { float inv = rsqrtf(n1); qr = mx.z*inv; qi = -mx.w*inv; }
      else { qr = 1.f; qi = 0.f; }
      float A0[4] = {s0.x, s0.y, s0.z, s0.w};
      float A1[4] = {s1.x, s1.y, s1.z, s1.w};
#pragma unroll
      for (int s = 0; s < 4; s++) {
        acc[s*4+0] += A0[s]*A0[s];
        acc[s*4+1] += A1[s]*A1[s];
        float aa = A0[s]*A1[s];
        acc[s*4+2] += aa * qr;
        acc[s*4+3] += aa * qi;
      }
    }
    float* pp = part + (((size_t)winid * RCH + chunk) * NB + f) * 16;
#pragma unroll
    for (int s = 0; s < 4; s++)
      *(float4*)(pp + s*4) = make_float4(acc[s*4+0], acc[s*4+1], acc[s*4+2], acc[s*4+3]);
  }
  // block-level max -> atomicMax (all threads participate)
  for (int off = 32; off; off >>= 1) mx2 = fmaxf(mx2, __shfl_xor(mx2, off));
  __shared__ float sm[4];
  if ((threadIdx.x & 63) == 0) sm[threadIdx.x >> 6] = mx2;
  __syncthreads();
  if (threadIdx.x == 0) {
    mx2 = fmaxf(fmaxf(sm[0], sm[1]), fmaxf(sm[2], sm[3]));
    atomicMax(c2max + winid, __float_as_uint(mx2));
  }
}

// ---- K2b: reduce partials + normalize -> Rbuf -----------------------------
__global__ __launch_bounds__(256) void k_rmat_red(const float* __restrict__ part,
                                                  const unsigned int* __restrict__ c2max,
                                                  float* __restrict__ Rbuf) {
  int idx = blockIdx.x * 256 + threadIdx.x;
  if (idx >= 4 * NB * 4) return;
  int s = idx & 3;
  int f = (idx >> 2) % NB;
  int winid = idx / (NB * 4);
  float4 a = make_float4(0.f, 0.f, 0.f, 0.f);
#pragma unroll
  for (int ch = 0; ch < RCH; ch++) {
    float4 p = *(const float4*)(part + (((size_t)winid * RCH + ch) * NB + f) * 16 + s * 4);
    a.x += p.x; a.y += p.y; a.z += p.z; a.w += p.w;
  }
  float c = fmaxf(1.f, sqrtf(__uint_as_float(c2max[winid])) * 0.1f);
  float W = c * c * EPSV + 0.5f * (a.x + a.y);
  float invW = 1.f / W;
  *(float4*)(Rbuf + ((size_t)winid * NB + f) * 16 + s * 4) =
      make_float4(a.x*invW, a.y*invW, a.z*invW, a.w*invW);
}

// ---- legacy K2 (fallback only) --------------------------------------------
__global__ __launch_bounds__(256) void k_rmat(const float* __restrict__ spec,
                                              const float* __restrict__ mix,
                                              const unsigned int* __restrict__ c2max,
                                              float* __restrict__ Rbuf) {
  int f = blockIdx.x;
  int winid = threadIdx.x >> 6;
  int lane = threadIdx.x & 63;
  int b = winid >> 1, w = winid & 1;
  float acc[16];
#pragma unroll
  for (int i = 0; i < 16; i++) acc[i] = 0.f;
  for (int tl = lane; tl < WINF; tl += 64) {
    int t = w * WINF + tl;
    size_t base = (size_t)(b * TF + t) * NB + f;
    const float4* sp = (const float4*)(spec + base * 8);
    float4 s0 = sp[0], s1 = sp[1];
    float4 mx = *(const float4*)(mix + base * 4);
    float n0 = mx.x*mx.x + mx.y*mx.y;
    float n1 = mx.z*mx.z + mx.w*mx.w;
    float qr, qi;
    if (n0 > 0.f && n1 > 0.f) {
      float inv = rsqrtf(n0 * n1);
      qr = (mx.x*mx.z + mx.y*mx.w) * inv;
      qi = (mx.y*mx.z - mx.x*mx.w) * inv;
    } else if (n0 > 0.f) { float inv = rsqrtf(n0); qr = mx.x*inv; qi = mx.y*inv; }
    else if (n1 > 0.f)   { float inv = rsqrtf(n1); qr = mx.z*inv; qi = -mx.w*inv; }
    else { qr = 1.f; qi = 0.f; }
    float A0[4] = {s0.x, s0.y, s0.z, s0.w};
    float A1[4] = {s1.x, s1.y, s1.z, s1.w};
#pragma unroll
    for (int s = 0; s < 4; s++) {
      acc[s*4+0] += A0[s]*A0[s];
      acc[s*4+1] += A1[s]*A1[s];
      float aa = A0[s]*A1[s];
      acc[s*4+2] += aa * qr;
      acc[s*4+3] += aa * qi;
    }
  }
#pragma unroll
  for (int i = 0; i < 16; i++) {
#pragma unroll
    for (int off = 32; off; off >>= 1) acc[i] += __shfl_xor(acc[i], off);
  }
  if (lane == 0) {
    float c = fmaxf(1.f, sqrtf(__uint_as_float(c2max[winid])) * 0.1f);
    float c2 = c * c;
#pragma unroll
    for (int s = 0; s < 4; s++) {
      float W = c2 * EPSV + 0.5f * (acc[s*4+0] + acc[s*4+1]);
      float invW = 1.f / W;
      *(float4*)(Rbuf + ((size_t)winid * NB + f) * 16 + s * 4) =
          make_float4(acc[s*4+0]*invW, acc[s*4+1]*invW, acc[s*4+2]*invW, acc[s*4+3]*invW);
    }
  }
}

// ---- K3: EM apply, write Y (fp16 complex), row stride ROWH2 ---------------
__global__ __launch_bounds__(256) void k_apply(const float* __restrict__ spec,
                                               const float* __restrict__ mix,
                                               const unsigned int* __restrict__ c2max,
                                               const float* __restrict__ Rbuf,
                                               __half2* __restrict__ Y) {
  size_t idx = (size_t)blockIdx.x * 256 + threadIdx.x;
  if (idx >= (size_t)2 * TF * NB) return;
  int f = (int)(idx % NB);
  int r = (int)(idx / NB);
  int t = r % TF, b = r / TF;
  int winid = b * 2 + (t >= WINF ? 1 : 0);
  float c = fmaxf(1.f, sqrtf(__uint_as_float(c2max[winid])) * 0.1f);
  float invc = 1.f / c, inv2c2 = 0.5f * invc * invc;
  size_t base = (size_t)(b * TF + t) * NB + f;
  const float4* sp = (const float4*)(spec + base * 8);
  float4 s0v = sp[0], s1v = sp[1];
  float4 mx = *(const float4*)(mix + base * 4);
  const float4* Rp = (const float4*)(Rbuf + ((size_t)winid * NB + f) * 16);
  float A0[4] = {s0v.x, s0v.y, s0v.z, s0v.w};
  float A1[4] = {s1v.x, s1v.y, s1v.z, s1v.w};
  float v[4]; float4 R[4];
  float C00 = SQEPS, C11 = SQEPS, C01r = 0.f, C01i = 0.f;
#pragma unroll
  for (int sq = 0; sq < 4; sq++) {
    R[sq] = Rp[sq];
    v[sq] = (A0[sq]*A0[sq] + A1[sq]*A1[sq]) * inv2c2;
    C00 += v[sq]*R[sq].x; C11 += v[sq]*R[sq].y;
    C01r += v[sq]*R[sq].z; C01i += v[sq]*R[sq].w;
  }
  float det = C00*C11 - (C01r*C01r + C01i*C01i);
  float invdet = 1.f / det;
  float x0r = mx.x*invc, x0i = mx.y*invc, x1r = mx.z*invc, x1i = mx.w*invc;
  float ix0r = (C11*x0r - (C01r*x1r - C01i*x1i)) * invdet;
  float ix0i = (C11*x0i - (C01r*x1i + C01i*x1r)) * invdet;
  float ix1r = (C00*x1r - (C01r*x0r + C01i*x0i)) * invdet;
  float ix1i = (C00*x1i - (C01r*x0i - C01i*x0r)) * invdet;
#pragma unroll
  for (int sq = 0; sq < 4; sq++) {
    float vc = v[sq] * c;
    float y0r = vc*(R[sq].x*ix0r + R[sq].z*ix1r - R[sq].w*ix1i);
    float y0i = vc*(R[sq].x*ix0i + R[sq].z*ix1i + R[sq].w*ix1r);
    float y1r = vc*(R[sq].z*ix0r + R[sq].w*ix0i + R[sq].y*ix1r);
    float y1i = vc*(R[sq].z*ix0i - R[sq].w*ix0r + R[sq].y*ix1i);
    size_t r0 = ((size_t)(((b * 4 + sq) * 2) * TF) + t) * ROWH2 + f;
    Y[r0] = __floats2half2_rn(y0r, y0i);
    Y[r0 + (size_t)TF * ROWH2] = __floats2half2_rn(y1r, y1i);
  }
}

// ---- inverse DFT-8 (unnormalized, e^{+i}) ---------------------------------
__device__ __forceinline__ void dft8(const float2* x, float2* X) {
  const float S2 = 0.70710678118654752f;
  float2 t0 = cadd(x[0], x[4]), t1 = csub(x[0], x[4]);
  float2 t2 = cadd(x[2], x[6]), t3 = csub(x[2], x[6]);
  float2 E0 = cadd(t0, t2), E2 = csub(t0, t2);
  float2 E1 = make_float2(t1.x - t3.y, t1.y + t3.x);
  float2 E3 = make_float2(t1.x + t3.y, t1.y - t3.x);
  float2 u0 = cadd(x[1], x[5]), u1 = csub(x[1], x[5]);
  float2 u2 = cadd(x[3], x[7]), u3 = csub(x[3], x[7]);
  float2 O0 = cadd(u0, u2), O2 = csub(u0, u2);
  float2 O1 = make_float2(u1.x - u3.y, u1.y + u3.x);
  float2 O3 = make_float2(u1.x + u3.y, u1.y - u3.x);
  float2 R1 = make_float2(S2*(O1.x - O1.y), S2*(O1.x + O1.y));   // e^{i pi/4} O1
  float2 R2 = make_float2(-O2.y, O2.x);                          // i O2
  float2 R3 = make_float2(-S2*(O3.x + O3.y), S2*(O3.x - O3.y));  // e^{i 3pi/4} O3
  X[0] = cadd(E0, O0); X[4] = csub(E0, O0);
  X[1] = cadd(E1, R1); X[5] = csub(E1, R1);
  X[2] = cadd(E2, R2); X[6] = csub(E2, R2);
  X[3] = cadd(E3, R3); X[7] = csub(E3, R3);
}

// radix-8 Stockham stage from registers, NS=1 (no twiddles)
__device__ __forceinline__ void r8_reg(const float2* x, float2* dst, int tid) {
  float2 X[8];
  dft8(x, X);
  const int d = tid << 3;
#pragma unroll
  for (int n = 0; n < 8; n++) dst[PADI(d + n)] = X[n];
}

// radix-8 Stockham stage, IN PLACE: block-wide read, barrier, block-wide write
template<int NS>
__device__ __forceinline__ void r8stage_ip(float2* __restrict__ buf, int tid) {
  const int q = tid;
  const int jm = q & (NS - 1);
  float2 x[8];
#pragma unroll
  for (int m = 0; m < 8; m++) x[m] = buf[PADI(q + (m << 8))];
  {
    float sn, cs;
    __sincosf((float)jm * (0.78539816339744831f / (float)NS), &sn, &cs); // 2pi/(8NS)
    const float2 w = make_float2(cs, sn);
    float2 wp = w;
    x[1] = cmul(x[1], wp);
#pragma unroll
    for (int m = 2; m < 8; m++) { wp = cmul(wp, w); x[m] = cmul(x[m], wp); }
  }
  float2 X[8];
  dft8(x, X);
  __syncthreads();   // all reads complete before any write (same buffer)
  const int d = ((q - jm) << 3) + jm;
#pragma unroll
  for (int n = 0; n < 8; n++) buf[PADI(d + n * NS)] = X[n];
}

// final radix-4 stage (NS=512) + Hann window + fp16 store (registers only)
__device__ __forceinline__ void r4_final(const float2* __restrict__ src,
                                         __half2* __restrict__ frow, int tid) {
  const float S2 = 0.70710678118654752f;
  // window weights (x 1/2048) for n2 = tid + 256*m, m=0..7; chained rotation pi/4
  float we[8], wo[8];
  float bsn, bcs;
  __sincosf((float)tid * 0.0030679615757712823f /* 2pi/2048 */, &bsn, &bcs);
  {
    float cs = bcs, sn = bsn;
    const float CD = 0.9999988234517019f, SD = 0.0015339801862847657f; // 2pi/4096
#pragma unroll
    for (int m = 0; m < 8; m++) {
      we[m] = (0.5f - 0.5f*cs) * (1.f/2048.f);
      float c1 = cs*CD - sn*SD;
      wo[m] = (0.5f - 0.5f*c1) * (1.f/2048.f);
      float ncs = (cs - sn) * S2;
      float nsn = (sn + cs) * S2;
      cs = ncs; sn = nsn;
    }
  }
  float2 w1 = make_float2(bcs, bsn);   // e^{i q pi/1024}, q=tid
#pragma unroll
  for (int qq = 0; qq < 2; qq++) {
    const int q = tid + (qq << 8);
    float2 v0 = src[PADI(q)];
    float2 v1 = src[PADI(q + 512)];
    float2 v2 = src[PADI(q + 1024)];
    float2 v3 = src[PADI(q + 1536)];
    float2 w2 = cmul(w1, w1);
    float2 w3 = cmul(w2, w1);
    v1 = cmul(v1, w1);
    v2 = cmul(v2, w2);
    v3 = cmul(v3, w3);
    float2 t0 = cadd(v0, v2), t1 = csub(v0, v2);
    float2 t2 = cadd(v1, v3), t3 = csub(v1, v3);
    float2 X0 = cadd(t0, t2);
    float2 X1 = make_float2(t1.x - t3.y, t1.y + t3.x);
    float2 X2 = csub(t0, t2);
    float2 X3 = make_float2(t1.x + t3.y, t1.y - t3.x);
    frow[q]        = __floats2half2_rn(X0.x*we[qq],     X0.y*wo[qq]);
    frow[q + 512]  = __floats2half2_rn(X1.x*we[qq + 2], X1.y*wo[qq + 2]);
    frow[q + 1024] = __floats2half2_rn(X2.x*we[qq + 4], X2.y*wo[qq + 4]);
    frow[q + 1536] = __floats2half2_rn(X3.x*we[qq + 6], X3.y*wo[qq + 6]);
    if (qq == 0)
      w1 = make_float2((w1.x - w1.y) * S2, (w1.y + w1.x) * S2); // *= e^{i pi/4}
  }
}

// ---- K4a: one block per (sid, t): irfft (radix 8,8,8,4) + window, in place -
// Single 17408 B LDS buffer; fold reads the Y row directly from global
// (both access patterns coalesced; mirror pass is an L1/L2 hit).
__global__ __launch_bounds__(256, 6) void k_frames(__half2* __restrict__ YF) {
  __shared__ float2 buf[2176];
  const int tid = threadIdx.x;
  const int t = blockIdx.x % TF;
  const int sid = blockIdx.x / TF;
  const size_t row = ((size_t)sid * TF + t) * ROWH2;
  const unsigned* Yu = (const unsigned*)(YF + row);

  // Hermitian fold straight into registers: x[m] = Z[tid + 256m]
  float2 x[8];
  {
    float sn, cs;
    __sincosf((float)tid * 0.0015339807878856412f /* pi/2048 */, &sn, &cs);
    const float R8c = 0.92387953251128676f, R8s = 0.38268343236508977f; // pi/8
#pragma unroll
    for (int m = 0; m < 8; m++) {
      const int k = tid + (m << 8);
      float2 Xa = h2f2(Yu[k]);
      float2 Xb = h2f2(Yu[2048 - k]);
      if (k == 0) { Xa.y = 0.f; Xb.y = 0.f; }
      float Sx = Xa.x + Xb.x, Sy = Xa.y - Xb.y;
      float Dx = Xa.x - Xb.x, Dy = Xa.y + Xb.y;
      x[m] = make_float2(0.5f*(Sx - sn*Dx - cs*Dy), 0.5f*(Sy + cs*Dx - sn*Dy));
      float ncs = cs*R8c - sn*R8s, nsn = sn*R8c + cs*R8s;
      cs = ncs; sn = nsn;
    }
  }
  r8_reg(x, buf, tid);     // NS=1 write (no prior LDS content)
  __syncthreads();
  r8stage_ip<8>(buf, tid);
  __syncthreads();
  r8stage_ip<64>(buf, tid);
  __syncthreads();
  r4_final(buf, YF + row, tid);   // NS=512 + window + store (in-place row)
}

// ---- K4b: gather overlap-add (4 frames) + wsum normalize, float4 stores ---
__global__ __launch_bounds__(256) void k_gather(const __half2* __restrict__ frames,
                                                float* __restrict__ out) {
  const int sid = blockIdx.x / 599;
  const int o4 = (blockIdx.x % 599) * 256 + threadIdx.x;   // 153344 quads/sid
  const int n = 2048 + 4 * o4;
  const int tbase = n >> 10;
  float s0 = 0.f, s1 = 0.f, s2 = 0.f, s3 = 0.f;
#pragma unroll
  for (int dt = 0; dt < 4; dt++) {
    int t = tbase - 3 + dt;
    if ((unsigned)t < (unsigned)TF) {
      int j2 = (n - (t << 10)) >> 1;   // even, 8B-aligned pair
      const __half2* fr = frames + ((size_t)sid * TF + t) * ROWH2 + j2;
      float2 va = __half22float2(fr[0]);
      float2 vb = __half22float2(fr[1]);
      s0 += va.x; s1 += va.y; s2 += vb.x; s3 += vb.y;
    }
  }
  float i0, i1, i2, i3;
  if (tbase >= 3 && tbase <= 599) {
    i0 = i1 = i2 = i3 = 2.f / 3.f;     // wsum exactly 1.5 interior
  } else {
    float w0 = 0.f, w1 = 0.f, w2 = 0.f, w3 = 0.f;
#pragma unroll
    for (int dt = 0; dt < 4; dt++) {
      int t = tbase - 3 + dt;
      if ((unsigned)t < (unsigned)TF) {
        int j = n - (t << 10);
        float a0 = 0.5f - 0.5f * __cosf((float)j * W4096);
        float a1 = 0.5f - 0.5f * __cosf((float)(j + 1) * W4096);
        float a2 = 0.5f - 0.5f * __cosf((float)(j + 2) * W4096);
        float a3 = 0.5f - 0.5f * __cosf((float)(j + 3) * W4096);
        w0 += a0*a0; w1 += a1*a1; w2 += a2*a2; w3 += a3*a3;
      }
    }
    i0 = 1.f / ((w0 > 1e-11f) ? w0 : 1.f);
    i1 = 1.f / ((w1 > 1e-11f) ? w1 : 1.f);
    i2 = 1.f / ((w2 > 1e-11f) ? w2 : 1.f);
    i3 = 1.f / ((w3 > 1e-11f) ? w3 : 1.f);
  }
  *(float4*)(out + (size_t)sid * ALEN + 4 * o4) =
      make_float4(s0 * i0, s1 * i1, s2 * i2, s3 * i3);
}

// ---- legacy fused path (fallback if ws too small) -------------------------
__device__ __forceinline__ float2 em_point_one(const float* __restrict__ spec,
    const float* __restrict__ mix, const float* __restrict__ Rbuf,
    const unsigned int* __restrict__ c2max, int b, int t, int f, int ssel, int ch) {
  int winid = b * 2 + (t >= WINF ? 1 : 0);
  float c = fmaxf(1.f, sqrtf(__uint_as_float(c2max[winid])) * 0.1f);
  float invc = 1.f / c, inv2c2 = 0.5f * invc * invc;
  size_t base = (size_t)(b * TF + t) * NB + f;
  const float4* sp = (const float4*)(spec + base * 8);
  float4 s0 = sp[0], s1 = sp[1];
  float4 mx = *(const float4*)(mix + base * 4);
  const float4* Rp = (const float4*)(Rbuf + ((size_t)winid * NB + f) * 16);
  float A0v[4] = {s0.x, s0.y, s0.z, s0.w};
  float A1v[4] = {s1.x, s1.y, s1.z, s1.w};
  float C00 = SQEPS, C11 = SQEPS, C01r = 0.f, C01i = 0.f;
  float vsel = 0.f; float4 Rsel = make_float4(0.f, 0.f, 0.f, 0.f);
#pragma unroll
  for (int sq = 0; sq < 4; sq++) {
    float4 R = Rp[sq];
    float v = (A0v[sq]*A0v[sq] + A1v[sq]*A1v[sq]) * inv2c2;
    C00 += v*R.x; C11 += v*R.y; C01r += v*R.z; C01i += v*R.w;
    if (sq == ssel) { vsel = v; Rsel = R; }
  }
  float det = C00*C11 - (C01r*C01r + C01i*C01i);
  float invdet = 1.f / det;
  float x0r = mx.x*invc, x0i = mx.y*invc, x1r = mx.z*invc, x1i = mx.w*invc;
  float ix0r = (C11*x0r - (C01r*x1r - C01i*x1i)) * invdet;
  float ix0i = (C11*x0i - (C01r*x1i + C01i*x1r)) * invdet;
  float ix1r = (C00*x1r - (C01r*x0r + C01i*x0i)) * invdet;
  float ix1i = (C00*x1i - (C01r*x0i - C01i*x0r)) * invdet;
  float vc = vsel * c;
  if (ch == 0)
    return make_float2(vc*(Rsel.x*ix0r + Rsel.z*ix1r - Rsel.w*ix1i),
                       vc*(Rsel.x*ix0i + Rsel.z*ix1i + Rsel.w*ix1r));
  return make_float2(vc*(Rsel.z*ix0r + Rsel.w*ix0i + Rsel.y*ix1r),
                     vc*(Rsel.z*ix0i - Rsel.w*ix0r + Rsel.y*ix1i));
}

template<int NS>
__device__ __forceinline__ void r4stage(const float2* __restrict__ src,
                                        float2* __restrict__ dst, int tid) {
#pragma unroll
  for (int qq = 0; qq < 2; qq++) {
    int q = tid + qq * 256;
    int jm = q & (NS - 1);
    float2 v0 = src[PADI(q)];
    float2 v1 = src[PADI(q + 512)];
    float2 v2 = src[PADI(q + 1024)];
    float2 v3 = src[PADI(q + 1536)];
    if constexpr (NS > 1) {
      float sn, cs;
      __sincosf((float)jm * (1.5707963267948966f / (float)NS), &sn, &cs);
      float2 w1 = make_float2(cs, sn);
      float2 w2 = cmul(w1, w1);
      float2 w3 = cmul(w2, w1);
      v1 = cmul(v1, w1);
      v2 = cmul(v2, w2);
      v3 = cmul(v3, w3);
    }
    float2 a0 = cadd(v0, v2), a1 = csub(v0, v2);
    float2 a2 = cadd(v1, v3), a3 = csub(v1, v3);
    int d = ((q - jm) << 2) + jm;
    dst[PADI(d)]        = cadd(a0, a2);
    dst[PADI(d + NS)]   = make_float2(a1.x - a3.y, a1.y + a3.x);
    dst[PADI(d + 2*NS)] = csub(a0, a2);
    dst[PADI(d + 3*NS)] = make_float2(a1.x + a3.y, a1.y - a3.x);
  }
}

__device__ __forceinline__ void r2stage(const float2* __restrict__ src,
                                        float2* __restrict__ dst, int tid) {
#pragma unroll
  for (int qq = 0; qq < 4; qq++) {
    int q = tid + qq * 256;
    float sn, cs;
    __sincosf((float)q * 0.003067961575771282f, &sn, &cs);
    float2 v0 = src[PADI(q)];
    float2 v1 = cmul(src[PADI(q + 1024)], make_float2(cs, sn));
    dst[PADI(q)]        = cadd(v0, v1);
    dst[PADI(q + 1024)] = csub(v0, v1);
  }
}

__global__ __launch_bounds__(256) void k_istft_fused(const float* __restrict__ spec,
        const float* __restrict__ mix, const unsigned int* __restrict__ c2max,
        const float* __restrict__ Rbuf, float* __restrict__ out) {
  __shared__ float2 bufA[2176];
  __shared__ float2 bufB[2176];
  const int tid = threadIdx.x;
  const int u = blockIdx.x % 150;
  const int sid = blockIdx.x / 150;
  const int b = sid >> 3;
  const int s = (sid >> 1) & 3;
  const int ch = sid & 1;
  float acc[16], wsm[16];
#pragma unroll
  for (int k = 0; k < 16; k++) { acc[k] = 0.f; wsm[k] = 0.f; }
  const int t0 = max(0, 4 * u - 1);
  const int t1 = min(TF - 1, 4 * u + 5);
  const int M0 = 2048 + u * 4096;
  for (int t = t0; t <= t1; ++t) {
    for (int k = tid; k < 2048; k += 256) {
      float2 Xa = em_point_one(spec, mix, Rbuf, c2max, b, t, k, s, ch);
      float2 Xb = em_point_one(spec, mix, Rbuf, c2max, b, t, 2048 - k, s, ch);
      if (k == 0) { Xa.y = 0.f; Xb.y = 0.f; }
      float Sx = Xa.x + Xb.x, Sy = Xa.y - Xb.y;
      float Dx = Xa.x - Xb.x, Dy = Xa.y + Xb.y;
      float sn, cs;
      __sincosf((float)k * 0.0015339807878856412f, &sn, &cs);
      bufA[PADI(k)] = make_float2(0.5f * (Sx - sn*Dx - cs*Dy),
                                  0.5f * (Sy + cs*Dx - sn*Dy));
    }
    __syncthreads();
    r4stage<1>(bufA, bufB, tid);   __syncthreads();
    r4stage<4>(bufB, bufA, tid);   __syncthreads();
    r4stage<16>(bufA, bufB, tid);  __syncthreads();
    r4stage<64>(bufB, bufA, tid);  __syncthreads();
    r4stage<256>(bufA, bufB, tid); __syncthreads();
    r2stage(bufB, bufA, tid);      __syncthreads();
    const int delta = M0 - t * HOP;
#pragma unroll
    for (int k2 = 0; k2 < 16; k2++) {
      int n = tid + 256 * k2 + delta;
      if (n >= 0 && n < NFFT) {
        float2 z = bufA[PADI(n >> 1)];
        float xn = (n & 1) ? z.y : z.x;
        float wn = 0.5f - 0.5f * __cosf((float)n * W4096);
        acc[k2] += xn * wn * (1.f / 2048.f);
        wsm[k2] += wn * wn;
      }
    }
    __syncthreads();
  }
#pragma unroll
  for (int k2 = 0; k2 < 16; k2++) {
    size_t o = (size_t)u * 4096 + tid + 256 * k2;
    if (o < (size_t)ALEN) {
      float wsv = wsm[k2];
      out[(size_t)sid * ALEN + o] = acc[k2] / (wsv > 1e-11f ? wsv : 1.f);
    }
  }
}

extern "C" void kernel_launch(void* const* d_in, const int* in_sizes, int n_in,
                              void* d_out, int out_size, void* d_ws, size_t ws_size,
                              hipStream_t stream) {
  const float* spec = (const float*)d_in[0];
  const float* mix  = (const float*)d_in[1];
  float* out = (float*)d_out;
  unsigned char* ws = (unsigned char*)d_ws;
  unsigned int* c2max = (unsigned int*)ws;         // 16 B
  float* Rbuf = (float*)(ws + 256);                // 524544 B
  __half2* Y = (__half2*)(ws + 524800);            // 16*600*2050*4 = 78.72 MB
  float* part = (float*)(ws + 524800);             // 10.5 MB, consumed before Y written
  const size_t needY = 524800 + (size_t)16 * TF * ROWH2 * 4;

  k_init<<<1, 256, 0, stream>>>(c2max);
  if (ws_size >= needY) {
    k_rmat_part<<<4 * RCH * 9, 256, 0, stream>>>(spec, mix, part, c2max);
    k_rmat_red<<<(4 * NB * 4 + 255) / 256, 256, 0, stream>>>(part, c2max, Rbuf);
    int total = 2 * TF * NB;
    k_apply<<<(total + 255) / 256, 256, 0, stream>>>(spec, mix, c2max, Rbuf, Y);
    k_frames<<<16 * TF, 256, 0, stream>>>(Y);
    k_gather<<<16 * 599, 256, 0, stream>>>(Y, out);
  } else {
    k_maxred<<<256, 256, 0, stream>>>(mix, c2max);
    k_rmat<<<NB, 256, 0, stream>>>(spec, mix, c2max, Rbuf);
    k_istft_fused<<<16 * 150, 256, 0, stream>>>(spec, mix, c2max, Rbuf, out);
  }
}